// Round 14
// baseline (506.685 us; speedup 1.0000x reference)
//
#include <hip/hip_runtime.h>

#define N_NODES 50000
#define N_EDGES 800000
#define IN_DIM 64
#define HID 128
#define NUM_LAYERS 4
#define NUM_GRAPHS 128
#define BN_EPS 1e-5f

typedef __attribute__((ext_vector_type(8))) short short8;
typedef __attribute__((ext_vector_type(4))) float f32x4;

__device__ inline unsigned short f2bf(float f) {
    unsigned int u = __float_as_uint(f);
    u += 0x7FFFu + ((u >> 16) & 1u);   // round-to-nearest-even
    return (unsigned short)(u >> 16);
}
__device__ inline float bflo(unsigned int p) { return __uint_as_float(p << 16); }
__device__ inline float bfhi(unsigned int p) { return __uint_as_float(p & 0xFFFF0000u); }
__device__ inline float bfch(const uint4& v, int c) {
    unsigned int p = (&v.x)[c >> 1];
    return (c & 1) ? bfhi(p) : bflo(p);
}

// ---------------- fused preprocessing: hist+rank, endpos, weight prep ----------------
__global__ void prep_kernel(const int* __restrict__ dst, int* __restrict__ cnt,
                            int* __restrict__ rank, const int* __restrict__ batch,
                            int* __restrict__ endpos, const float* __restrict__ W_in,
                            const float* __restrict__ conv_W1,
                            const float* __restrict__ conv_W2,
                            unsigned short* __restrict__ wt_in,
                            unsigned short* __restrict__ wt1,
                            unsigned short* __restrict__ wt2) {
    int tid = threadIdx.x;
    // hist + rank (4 independent atomic chains per thread)
    int base = blockIdx.x * 1024 + tid;
#pragma unroll
    for (int u = 0; u < 4; ++u) {
        int e = base + u * 256;
        if (e < N_EDGES) rank[e] = atomicAdd(&cnt[dst[e]], 1);
    }
    int i = blockIdx.x * 256 + tid;
    // endpos (batch sorted; write only at run boundaries)
    if (i < N_NODES) {
        int b = batch[i];
        int b1 = (i + 1 < N_NODES) ? batch[i + 1] : NUM_GRAPHS;
        for (int g = b; g < b1; ++g) endpos[g] = i + 1;
        if (i == 0)
            for (int g = 0; g < b; ++g) endpos[g] = 0;
    }
    // weight transpose + cvt to bf16
    if (i < 128 * IN_DIM) {
        int c = i >> 6, k = i & 63;
        wt_in[i] = f2bf(W_in[k * HID + c]);
    }
    if (i < 4 * HID * HID) {
        int o = i & (HID * HID - 1);
        int layer = i >> 14;
        int c = o >> 7, k = o & 127;
        wt1[i] = f2bf(conv_W1[layer * HID * HID + k * HID + c]);
        wt2[i] = f2bf(conv_W2[layer * HID * HID + k * HID + c]);
    }
}

// ---------------- 2-stage coalesced exclusive scan over 50000 counters ----------------
#define SCAN_BLOCKS ((N_NODES + 1023) / 1024)   // 49

__global__ __launch_bounds__(1024) void scan1_kernel(const int* __restrict__ cnt,
                                                     int* __restrict__ bsum) {
    __shared__ int ls[1024];
    int t = threadIdx.x;
    int g = blockIdx.x * 1024 + t;
    int v = (g < N_NODES) ? cnt[g] : 0;
    ls[t] = v;
    __syncthreads();
    for (int off = 512; off > 0; off >>= 1) {
        if (t < off) ls[t] += ls[t + off];
        __syncthreads();
    }
    if (t == 0) bsum[blockIdx.x] = ls[0];
}

// scan within block + inline cross-block offset (wave64 reduce over bsum[0..bid))
__global__ __launch_bounds__(1024) void scan3_kernel(const int* __restrict__ cnt,
                                                     const int* __restrict__ bsum,
                                                     int* __restrict__ row_start) {
    __shared__ int ls[1024];
    __shared__ int boffS;
    int t = threadIdx.x;
    if (t < 64) {
        int v2 = (t < blockIdx.x && t < SCAN_BLOCKS) ? bsum[t] : 0;
#pragma unroll
        for (int off = 32; off > 0; off >>= 1) v2 += __shfl_down(v2, off);
        if (t == 0) boffS = v2;
    }
    int g = blockIdx.x * 1024 + t;
    int v = (g < N_NODES) ? cnt[g] : 0;
    ls[t] = v;
    __syncthreads();
    for (int off = 1; off < 1024; off <<= 1) {
        int x = (t >= off) ? ls[t - off] : 0;
        __syncthreads();
        ls[t] += x;
        __syncthreads();
    }
    int excl = ls[t] - v + boffS;
    if (g < N_NODES) {
        row_start[g] = excl;
        if (g == N_NODES - 1) row_start[N_NODES] = excl + v;
    }
}

// atomic-free CSR fill, 8B record = {src, bf16(ea.x) | bf16(ea.y)<<16}
__global__ void fill_kernel(const int* __restrict__ src, const int* __restrict__ dst,
                            const float* __restrict__ ea, const int* __restrict__ rank,
                            const int* __restrict__ row_start, int2* __restrict__ edges) {
    int e = blockIdx.x * 256 + threadIdx.x;
    if (e >= N_EDGES) return;
    float2 a = *(const float2*)&ea[2 * e];
    int p = row_start[dst[e]] + rank[e];
    unsigned int pk = (unsigned int)f2bf(a.x) | ((unsigned int)f2bf(a.y) << 16);
    edges[p] = make_int2(src[e], (int)pk);
}

// gbf[n] = bf16(hbf[n] + vnb[batch[n]])  -- pre-combined gather table for aggr
__global__ void hvadd_kernel(const unsigned short* __restrict__ hbf,
                             const unsigned short* __restrict__ vnb,
                             const int* __restrict__ batch,
                             unsigned short* __restrict__ gbf) {
    int idx = blockIdx.x * 256 + threadIdx.x;   // over N_NODES*16
    int n = idx >> 4;
    if (n >= N_NODES) return;
    int cg = (idx & 15) * 8;
    uint4 h = *(const uint4*)&hbf[(size_t)n * HID + cg];
    uint4 v = *(const uint4*)&vnb[(size_t)batch[n] * HID + cg];
    unsigned int o[4];
#pragma unroll
    for (int p = 0; p < 4; ++p) {
        float lo = bflo((&h.x)[p]) + bflo((&v.x)[p]);
        float hi = bfhi((&h.x)[p]) + bfhi((&v.x)[p]);
        o[p] = (unsigned int)f2bf(lo) | ((unsigned int)f2bf(hi) << 16);
    }
    *(uint4*)&gbf[(size_t)n * HID + cg] = make_uint4(o[0], o[1], o[2], o[3]);
}

// ---------------- edge aggregation (16 threads/node, 8-deep pipeline) ----------------
// z[n] = g[n] + sum_edges relu(g[src] + ea@We + be); bf16 in/out.
// Each thread owns 8 channels across ALL edges of its node (no cross-lane reduce).
__global__ __launch_bounds__(256) void aggr_kernel(const unsigned short* __restrict__ gbf,
                                                   const int2* __restrict__ edges,
                                                   const int* __restrict__ row_start,
                                                   const float* __restrict__ We,
                                                   const float* __restrict__ be,
                                                   unsigned short* __restrict__ zbf,
                                                   float* __restrict__ S1,
                                                   float* __restrict__ S2) {
    int tid = threadIdx.x;
    if (blockIdx.x == 0 && tid < HID) {   // zero BN stat accumulators for this layer
        S1[tid] = 0.f;
        S2[tid] = 0.f;
    }
    int cg = (tid & 15) * 8;               // 8-channel group
    int n = blockIdx.x * 16 + (tid >> 4);  // grid exact: 3125*16 = 50000

    float w0[8], w1[8], bc[8];
    {
        float4 a0 = *(const float4*)&We[cg], a1 = *(const float4*)&We[cg + 4];
        float4 b0 = *(const float4*)&We[HID + cg], b1v = *(const float4*)&We[HID + cg + 4];
        float4 c0 = *(const float4*)&be[cg], c1 = *(const float4*)&be[cg + 4];
        w0[0]=a0.x; w0[1]=a0.y; w0[2]=a0.z; w0[3]=a0.w; w0[4]=a1.x; w0[5]=a1.y; w0[6]=a1.z; w0[7]=a1.w;
        w1[0]=b0.x; w1[1]=b0.y; w1[2]=b0.z; w1[3]=b0.w; w1[4]=b1v.x; w1[5]=b1v.y; w1[6]=b1v.z; w1[7]=b1v.w;
        bc[0]=c0.x; bc[1]=c0.y; bc[2]=c0.z; bc[3]=c0.w; bc[4]=c1.x; bc[5]=c1.y; bc[6]=c1.z; bc[7]=c1.w;
    }

    uint4 hs = *(const uint4*)&gbf[(size_t)n * HID + cg];   // self term (issued early)
    int jb = row_start[n], je = row_start[n + 1];
    float acc[8];
#pragma unroll
    for (int c = 0; c < 8; ++c) acc[c] = 0.f;

    int j = jb;
    for (; j + 8 <= je; j += 8) {
        int2 q[8];
        uint4 hq[8];
#pragma unroll
        for (int u = 0; u < 8; ++u) q[u] = edges[j + u];
#pragma unroll
        for (int u = 0; u < 8; ++u) hq[u] = *(const uint4*)&gbf[(size_t)q[u].x * HID + cg];
#pragma unroll
        for (int u = 0; u < 8; ++u) {
            float ex = bflo((unsigned int)q[u].y), ey = bfhi((unsigned int)q[u].y);
#pragma unroll
            for (int c = 0; c < 8; ++c)
                acc[c] += fmaxf(bfch(hq[u], c) + fmaf(ex, w0[c], fmaf(ey, w1[c], bc[c])), 0.f);
        }
    }
    if (j + 4 <= je) {
        int2 q[4];
        uint4 hq[4];
#pragma unroll
        for (int u = 0; u < 4; ++u) q[u] = edges[j + u];
#pragma unroll
        for (int u = 0; u < 4; ++u) hq[u] = *(const uint4*)&gbf[(size_t)q[u].x * HID + cg];
#pragma unroll
        for (int u = 0; u < 4; ++u) {
            float ex = bflo((unsigned int)q[u].y), ey = bfhi((unsigned int)q[u].y);
#pragma unroll
            for (int c = 0; c < 8; ++c)
                acc[c] += fmaxf(bfch(hq[u], c) + fmaf(ex, w0[c], fmaf(ey, w1[c], bc[c])), 0.f);
        }
        j += 4;
    }
    for (; j < je; ++j) {
        int2 q = edges[j];
        uint4 hq = *(const uint4*)&gbf[(size_t)q.x * HID + cg];
        float ex = bflo((unsigned int)q.y), ey = bfhi((unsigned int)q.y);
#pragma unroll
        for (int c = 0; c < 8; ++c)
            acc[c] += fmaxf(bfch(hq, c) + fmaf(ex, w0[c], fmaf(ey, w1[c], bc[c])), 0.f);
    }

    unsigned int o[4];
#pragma unroll
    for (int p = 0; p < 4; ++p)
        o[p] = (unsigned int)f2bf(bflo((&hs.x)[p]) + acc[2 * p]) |
               ((unsigned int)f2bf(bfhi((&hs.x)[p]) + acc[2 * p + 1]) << 16);
    *(uint4*)&zbf[(size_t)n * HID + cg] = make_uint4(o[0], o[1], o[2], o[3]);
}

// ---------------- input GEMM (bf16 MFMA): hbf = bf16(x @ W_in + b_in) ----------------
__global__ __launch_bounds__(256) void ingemm_kernel(const float* __restrict__ A,
                                                     const unsigned short* __restrict__ Wt,
                                                     const float* __restrict__ bias,
                                                     unsigned short* __restrict__ outbf) {
    constexpr int KD = IN_DIM;
    __shared__ unsigned short aS[64 * KD];
    __shared__ unsigned short wS[128 * KD];
    int tid = threadIdx.x;
    int row0 = blockIdx.x * 64;

#pragma unroll
    for (int it = 0; it < (64 * KD) / (256 * 4); ++it) {
        int idx = it * 1024 + tid * 4;
        int r = idx / KD, k = idx % KD;
        int grow = row0 + r;
        float4 v = (grow < N_NODES) ? *(const float4*)&A[(size_t)grow * KD + k]
                                    : make_float4(0.f, 0.f, 0.f, 0.f);
        unsigned int d0 = (unsigned int)f2bf(v.x) | ((unsigned int)f2bf(v.y) << 16);
        unsigned int d1 = (unsigned int)f2bf(v.z) | ((unsigned int)f2bf(v.w) << 16);
        unsigned int byte = (unsigned int)(idx * 2) ^ (unsigned int)((r & 7) << 4);
        *(uint2*)((char*)aS + byte) = make_uint2(d0, d1);
    }
#pragma unroll
    for (int it = 0; it < (128 * KD) / (256 * 8); ++it) {
        int idx = it * 2048 + tid * 8;
        int c = idx / KD;
        uint4 v = *(const uint4*)&Wt[idx];
        unsigned int byte = (unsigned int)(idx * 2) ^ (unsigned int)((c & 7) << 4);
        *(uint4*)((char*)wS + byte) = v;
    }
    __syncthreads();

    int w = tid >> 6, l = tid & 63;
    int wr = w >> 1, wc = w & 1, lr = l & 15, kq = (l >> 4) * 8;
    f32x4 acc[2][4];
#pragma unroll
    for (int r = 0; r < 2; ++r)
#pragma unroll
        for (int t = 0; t < 4; ++t) acc[r][t] = (f32x4){0.f, 0.f, 0.f, 0.f};

#pragma unroll
    for (int sstep = 0; sstep < KD / 32; ++sstep) {
        int k0 = sstep * 32 + kq;
        int ar0 = 32 * wr + lr, ar1 = ar0 + 16;
        short8 af0 = *(short8*)((char*)aS + ((unsigned int)((ar0 * KD + k0) * 2) ^
                                            (unsigned int)((ar0 & 7) << 4)));
        short8 af1 = *(short8*)((char*)aS + ((unsigned int)((ar1 * KD + k0) * 2) ^
                                            (unsigned int)((ar1 & 7) << 4)));
#pragma unroll
        for (int t = 0; t < 4; ++t) {
            int col = 64 * wc + 16 * t + lr;
            short8 bf = *(short8*)((char*)wS + ((unsigned int)((col * KD + k0) * 2) ^
                                               (unsigned int)((col & 7) << 4)));
            acc[0][t] = __builtin_amdgcn_mfma_f32_16x16x32_bf16(af0, bf, acc[0][t], 0, 0, 0);
            acc[1][t] = __builtin_amdgcn_mfma_f32_16x16x32_bf16(af1, bf, acc[1][t], 0, 0, 0);
        }
    }
#pragma unroll
    for (int r = 0; r < 2; ++r) {
        int rbase = row0 + 32 * wr + 16 * r + (l >> 4) * 4;
#pragma unroll
        for (int t = 0; t < 4; ++t) {
            int col = 64 * wc + 16 * t + lr;
            float b = bias[col];
#pragma unroll
            for (int q = 0; q < 4; ++q) {
                int grow = rbase + q;
                if (grow < N_NODES) outbf[(size_t)grow * HID + col] = f2bf(acc[r][t][q] + b);
            }
        }
    }
}

// ---------------- fused conv MLP: z2 = relu(z@W1+b1)@W2+b2, + BN stats ----------------
// 128x128 tile, 512 threads = 8 waves (2x4). y lives in LDS (reuses z tile).
// BN stats shuffle-reduced across the 4 same-column lanes before LDS atomics.
__global__ __launch_bounds__(512) void conv_kernel(const unsigned short* __restrict__ zbf,
                                                   const unsigned short* __restrict__ Wt1,
                                                   const float* __restrict__ b1,
                                                   const unsigned short* __restrict__ Wt2,
                                                   const float* __restrict__ b2,
                                                   unsigned short* __restrict__ z2bf,
                                                   float* __restrict__ S1,
                                                   float* __restrict__ S2,
                                                   float* __restrict__ zinit, int zinit_n) {
    constexpr int KD = HID;
    __shared__ unsigned short aS[128 * KD];   // z tile, then y tile (32 KB)
    __shared__ unsigned short wS[128 * KD];   // W1, then W2 (32 KB)
    __shared__ float sh1[HID], sh2[HID];
    int tid = threadIdx.x;
    if (zinit && blockIdx.x == 0)
        for (int i = tid; i < zinit_n; i += 512) zinit[i] = 0.f;
    if (tid < HID) { sh1[tid] = 0.f; sh2[tid] = 0.f; }

    int row0 = blockIdx.x * 128;

#pragma unroll
    for (int it = 0; it < 4; ++it) {          // 128*128/(512*8)
        int idx = it * 4096 + tid * 8;
        int r = idx >> 7;
        int grow = row0 + r;
        uint4 v = (grow < N_NODES) ? *(const uint4*)&zbf[(size_t)grow * HID + (idx & 127)]
                                   : make_uint4(0u, 0u, 0u, 0u);
        unsigned int byte = (unsigned int)(idx * 2) ^ (unsigned int)((r & 7) << 4);
        *(uint4*)((char*)aS + byte) = v;
    }
#pragma unroll
    for (int it = 0; it < 4; ++it) {
        int idx = it * 4096 + tid * 8;
        int c = idx >> 7;
        uint4 v = *(const uint4*)&Wt1[idx];
        unsigned int byte = (unsigned int)(idx * 2) ^ (unsigned int)((c & 7) << 4);
        *(uint4*)((char*)wS + byte) = v;
    }
    __syncthreads();

    int w = tid >> 6, l = tid & 63;
    int wr = w >> 2, wc = w & 3;       // 2x4 wave grid: 64 rows x 32 cols per wave
    int lr = l & 15, kq = (l >> 4) * 8;

    f32x4 acc[4][2];
#pragma unroll
    for (int rt = 0; rt < 4; ++rt)
#pragma unroll
        for (int ct = 0; ct < 2; ++ct) acc[rt][ct] = (f32x4){0.f, 0.f, 0.f, 0.f};

#pragma unroll
    for (int sstep = 0; sstep < 4; ++sstep) {
        int k0 = sstep * 32 + kq;
        short8 af[4];
#pragma unroll
        for (int rt = 0; rt < 4; ++rt) {
            int ar = 64 * wr + 16 * rt + lr;
            af[rt] = *(short8*)((char*)aS + ((unsigned int)((ar * KD + k0) * 2) ^
                                            (unsigned int)((ar & 7) << 4)));
        }
#pragma unroll
        for (int ct = 0; ct < 2; ++ct) {
            int col = 32 * wc + 16 * ct + lr;
            short8 bf = *(short8*)((char*)wS + ((unsigned int)((col * KD + k0) * 2) ^
                                               (unsigned int)((col & 7) << 4)));
#pragma unroll
            for (int rt = 0; rt < 4; ++rt)
                acc[rt][ct] = __builtin_amdgcn_mfma_f32_16x16x32_bf16(af[rt], bf, acc[rt][ct], 0, 0, 0);
        }
    }
    __syncthreads();   // everyone done reading aS (z) and wS (W1)

    // y = relu(acc + b1) -> aS (bf16, swizzled); stage W2 -> wS
#pragma unroll
    for (int rt = 0; rt < 4; ++rt) {
        int lrow0 = 64 * wr + 16 * rt + (l >> 4) * 4;
#pragma unroll
        for (int ct = 0; ct < 2; ++ct) {
            int col = 32 * wc + 16 * ct + lr;
            float b = b1[col];
#pragma unroll
            for (int q = 0; q < 4; ++q) {
                int lrow = lrow0 + q;
                float v = fmaxf(acc[rt][ct][q] + b, 0.f);
                unsigned int byte = (unsigned int)((lrow * KD + col) * 2) ^
                                    (unsigned int)((lrow & 7) << 4);
                *(unsigned short*)((char*)aS + byte) = f2bf(v);
            }
        }
    }
#pragma unroll
    for (int it = 0; it < 4; ++it) {
        int idx = it * 4096 + tid * 8;
        int c = idx >> 7;
        uint4 v = *(const uint4*)&Wt2[idx];
        unsigned int byte = (unsigned int)(idx * 2) ^ (unsigned int)((c & 7) << 4);
        *(uint4*)((char*)wS + byte) = v;
    }
    __syncthreads();

    f32x4 acc2[4][2];
#pragma unroll
    for (int rt = 0; rt < 4; ++rt)
#pragma unroll
        for (int ct = 0; ct < 2; ++ct) acc2[rt][ct] = (f32x4){0.f, 0.f, 0.f, 0.f};

#pragma unroll
    for (int sstep = 0; sstep < 4; ++sstep) {
        int k0 = sstep * 32 + kq;
        short8 af[4];
#pragma unroll
        for (int rt = 0; rt < 4; ++rt) {
            int ar = 64 * wr + 16 * rt + lr;
            af[rt] = *(short8*)((char*)aS + ((unsigned int)((ar * KD + k0) * 2) ^
                                            (unsigned int)((ar & 7) << 4)));
        }
#pragma unroll
        for (int ct = 0; ct < 2; ++ct) {
            int col = 32 * wc + 16 * ct + lr;
            short8 bf = *(short8*)((char*)wS + ((unsigned int)((col * KD + k0) * 2) ^
                                               (unsigned int)((col & 7) << 4)));
#pragma unroll
            for (int rt = 0; rt < 4; ++rt)
                acc2[rt][ct] = __builtin_amdgcn_mfma_f32_16x16x32_bf16(af[rt], bf, acc2[rt][ct], 0, 0, 0);
        }
    }

    // epilogue: z2 = acc2 + b2 -> z2bf (bf16) + BN stats (register acc + shuffle reduce)
    float s1v[2] = {0.f, 0.f}, s2v[2] = {0.f, 0.f};
#pragma unroll
    for (int rt = 0; rt < 4; ++rt) {
        int rbase = row0 + 64 * wr + 16 * rt + (l >> 4) * 4;
#pragma unroll
        for (int ct = 0; ct < 2; ++ct) {
            int col = 32 * wc + 16 * ct + lr;
            float b = b2[col];
#pragma unroll
            for (int q = 0; q < 4; ++q) {
                int grow = rbase + q;
                if (grow < N_NODES) {
                    float v = acc2[rt][ct][q] + b;
                    z2bf[(size_t)grow * HID + col] = f2bf(v);
                    s1v[ct] += v;
                    s2v[ct] += v * v;
                }
            }
        }
    }
#pragma unroll
    for (int ct = 0; ct < 2; ++ct) {
        float a = s1v[ct], bsum2 = s2v[ct];
        a += __shfl_xor(a, 16); a += __shfl_xor(a, 32);
        bsum2 += __shfl_xor(bsum2, 16); bsum2 += __shfl_xor(bsum2, 32);
        if ((l >> 4) == 0) {
            int col = 32 * wc + 16 * ct + lr;
            atomicAdd(&sh1[col], a);
            atomicAdd(&sh2[col], bsum2);
        }
    }
    __syncthreads();
    if (tid < HID) {
        atomicAdd(&S1[tid], sh1[tid]);
        atomicAdd(&S2[tid], sh2[tid]);
    }
}

// ---------------- BN apply + relu -> hbf (bf16) + segment-sum into vn_up/pool ----------------
__global__ __launch_bounds__(256) void bn_kernel(const unsigned short* __restrict__ z2bf,
                                                 const float* __restrict__ S1,
                                                 const float* __restrict__ S2,
                                                 const float* __restrict__ gma,
                                                 const float* __restrict__ bta,
                                                 const int* __restrict__ batch,
                                                 unsigned short* __restrict__ hbf,
                                                 float* __restrict__ up) {
    int tid = threadIdx.x;
    int cg = (tid & 31) * 4;
    int n0 = (blockIdx.x * 8 + (tid >> 5)) * 16;
    const float inv = 1.f / (float)N_NODES;
    float4 s1 = *(const float4*)&S1[cg];
    float4 s2 = *(const float4*)&S2[cg];
    float4 g4 = *(const float4*)&gma[cg];
    float4 b4 = *(const float4*)&bta[cg];
    float mux = s1.x * inv, muy = s1.y * inv, muz = s1.z * inv, muw = s1.w * inv;
    float gmx = g4.x * rsqrtf(s2.x * inv - mux * mux + BN_EPS);
    float gmy = g4.y * rsqrtf(s2.y * inv - muy * muy + BN_EPS);
    float gmz = g4.z * rsqrtf(s2.z * inv - muz * muz + BN_EPS);
    float gmw = g4.w * rsqrtf(s2.w * inv - muw * muw + BN_EPS);

    float4 acc = make_float4(0.f, 0.f, 0.f, 0.f);
    int gcur = -1;
    for (int i = 0; i < 16; ++i) {
        int n = n0 + i;
        if (n >= N_NODES) break;
        uint2 zv = *(const uint2*)&z2bf[(size_t)n * HID + cg];
        float4 hn;
        hn.x = fmaxf(fmaf(bflo(zv.x) - mux, gmx, b4.x), 0.f);
        hn.y = fmaxf(fmaf(bfhi(zv.x) - muy, gmy, b4.y), 0.f);
        hn.z = fmaxf(fmaf(bflo(zv.y) - muz, gmz, b4.z), 0.f);
        hn.w = fmaxf(fmaf(bfhi(zv.y) - muw, gmw, b4.w), 0.f);
        uint2 pk;
        pk.x = (unsigned int)f2bf(hn.x) | ((unsigned int)f2bf(hn.y) << 16);
        pk.y = (unsigned int)f2bf(hn.z) | ((unsigned int)f2bf(hn.w) << 16);
        *(uint2*)&hbf[(size_t)n * HID + cg] = pk;
        int gb = batch[n];
        if (gb != gcur) {
            if (gcur >= 0) {
                atomicAdd(&up[gcur * HID + cg + 0], acc.x);
                atomicAdd(&up[gcur * HID + cg + 1], acc.y);
                atomicAdd(&up[gcur * HID + cg + 2], acc.z);
                atomicAdd(&up[gcur * HID + cg + 3], acc.w);
            }
            acc = make_float4(0.f, 0.f, 0.f, 0.f);
            gcur = gb;
        }
        acc.x += hn.x; acc.y += hn.y; acc.z += hn.z; acc.w += hn.w;
    }
    if (gcur >= 0) {
        atomicAdd(&up[gcur * HID + cg + 0], acc.x);
        atomicAdd(&up[gcur * HID + cg + 1], acc.y);
        atomicAdd(&up[gcur * HID + cg + 2], acc.z);
        atomicAdd(&up[gcur * HID + cg + 3], acc.w);
    }
}

// ---------------- virtual-node MLP: vn += relu(up@W1+b1)@W2+b2; also bf16 copy ----------------
__global__ __launch_bounds__(128) void vnmlp_kernel(const float* __restrict__ up,
                                                    const float* __restrict__ W1,
                                                    const float* __restrict__ b1,
                                                    const float* __restrict__ W2,
                                                    const float* __restrict__ b2,
                                                    float* __restrict__ vn,
                                                    unsigned short* __restrict__ vnb) {
    __shared__ float t[HID];
    int g = blockIdx.x, c = threadIdx.x;
    float s = b1[c];
#pragma unroll 8
    for (int k = 0; k < HID; ++k) s = fmaf(up[g * HID + k], W1[k * HID + c], s);
    t[c] = fmaxf(s, 0.f);
    __syncthreads();
    float s2 = b2[c];
#pragma unroll 8
    for (int k = 0; k < HID; ++k) s2 = fmaf(t[k], W2[k * HID + c], s2);
    float nv = vn[g * HID + c] + s2;
    vn[g * HID + c] = nv;
    vnb[g * HID + c] = f2bf(nv);
}

// ---------------- classifier: logits[g] ----------------
__global__ __launch_bounds__(128) void cls_kernel(const float* __restrict__ pool,
                                                  const int* __restrict__ endpos,
                                                  const float* __restrict__ W1,
                                                  const float* __restrict__ b1,
                                                  const float* __restrict__ W2,
                                                  const float* __restrict__ b2,
                                                  float* __restrict__ out) {
    __shared__ float t[HID];
    __shared__ float red[HID];
    int g = blockIdx.x, c = threadIdx.x;
    int cnt = endpos[g] - (g > 0 ? endpos[g - 1] : 0);
    float cntf = fmaxf((float)cnt, 1.f);
    t[c] = pool[g * HID + c] / cntf;
    __syncthreads();
    float s = b1[c];
#pragma unroll 8
    for (int k = 0; k < HID; ++k) s = fmaf(t[k], W1[k * HID + c], s);
    float y = fmaxf(s, 0.f);
    red[c] = y * W2[c];
    __syncthreads();
    for (int off = 64; off > 0; off >>= 1) {
        if (c < off) red[c] += red[c + off];
        __syncthreads();
    }
    if (c == 0) out[g] = red[0] + b2[0];
}

// ---------------- host-side orchestration ----------------
extern "C" void kernel_launch(void* const* d_in, const int* in_sizes, int n_in,
                              void* d_out, int out_size, void* d_ws, size_t ws_size,
                              hipStream_t stream) {
    const float* x        = (const float*)d_in[0];
    const float* edge_attr= (const float*)d_in[1];
    const int*   edge_idx = (const int*)d_in[2];
    const int*   batch    = (const int*)d_in[3];
    const float* W_in     = (const float*)d_in[4];
    const float* b_in     = (const float*)d_in[5];
    const float* W_e      = (const float*)d_in[6];
    const float* b_e      = (const float*)d_in[7];
    const float* conv_W1  = (const float*)d_in[8];
    const float* conv_b1  = (const float*)d_in[9];
    const float* conv_W2  = (const float*)d_in[10];
    const float* conv_b2  = (const float*)d_in[11];
    const float* bn_g     = (const float*)d_in[12];
    const float* bn_b     = (const float*)d_in[13];
    const float* vn_W1    = (const float*)d_in[14];
    const float* vn_b1    = (const float*)d_in[15];
    const float* vn_W2    = (const float*)d_in[16];
    const float* vn_b2    = (const float*)d_in[17];
    const float* cls_W1   = (const float*)d_in[18];
    const float* cls_b1   = (const float*)d_in[19];
    const float* cls_W2   = (const float*)d_in[20];
    const float* cls_b2   = (const float*)d_in[21];

    char* ws = (char*)d_ws;
    size_t off = 0;
    auto alloc = [&](size_t bytes) -> void* {
        void* p = ws + off;
        off = (off + bytes + 255) & ~(size_t)255;
        return p;
    };
    unsigned short* z2bf = (unsigned short*)alloc((size_t)N_NODES * HID * 2);
    unsigned short* hbf = (unsigned short*)alloc((size_t)N_NODES * HID * 2);
    unsigned short* gbf = (unsigned short*)alloc((size_t)N_NODES * HID * 2);
    unsigned short* zbf = (unsigned short*)alloc((size_t)N_NODES * HID * 2);
    size_t zero_begin = off;
    int*   cnt    = (int*)alloc((size_t)N_NODES * 4);
    float* vn     = (float*)alloc((size_t)NUM_GRAPHS * HID * 4);
    unsigned short* vnb = (unsigned short*)alloc((size_t)NUM_GRAPHS * HID * 2);
    float* pool   = (float*)alloc((size_t)NUM_GRAPHS * HID * 4);
    size_t zero_end = off;
    int*    endpos    = (int*)alloc((size_t)NUM_GRAPHS * 4);
    int*    row_start = (int*)alloc((size_t)(N_NODES + 1) * 4);
    int*    rank      = (int*)alloc((size_t)N_EDGES * 4);
    int2*   edges     = (int2*)alloc((size_t)N_EDGES * 8);
    float*  vn_up     = (float*)alloc((size_t)NUM_GRAPHS * HID * 4);
    float*  S1        = (float*)alloc((size_t)HID * 4);
    float*  S2        = (float*)alloc((size_t)HID * 4);
    int*    bsum      = (int*)alloc((size_t)SCAN_BLOCKS * 4);
    unsigned short* wt_in = (unsigned short*)alloc((size_t)HID * IN_DIM * 2);
    unsigned short* wt1   = (unsigned short*)alloc((size_t)NUM_LAYERS * HID * HID * 2);
    unsigned short* wt2   = (unsigned short*)alloc((size_t)NUM_LAYERS * HID * HID * 2);
    (void)ws_size; (void)in_sizes; (void)n_in; (void)out_size;

    const int* srcp = edge_idx;
    const int* dstp = edge_idx + N_EDGES;

    hipMemsetAsync(ws + zero_begin, 0, zero_end - zero_begin, stream);
    prep_kernel<<<(N_EDGES + 1023) / 1024, 256, 0, stream>>>(dstp, cnt, rank, batch, endpos,
                                                             W_in, conv_W1, conv_W2,
                                                             wt_in, wt1, wt2);
    scan1_kernel<<<SCAN_BLOCKS, 1024, 0, stream>>>(cnt, bsum);
    scan3_kernel<<<SCAN_BLOCKS, 1024, 0, stream>>>(cnt, bsum, row_start);
    fill_kernel<<<(N_EDGES + 255) / 256, 256, 0, stream>>>(srcp, dstp, edge_attr, rank,
                                                           row_start, edges);

    ingemm_kernel<<<(N_NODES + 63) / 64, 256, 0, stream>>>(x, wt_in, b_in, hbf);

    const int conv_grid = (N_NODES + 127) / 128;   // 391
    for (int i = 0; i < NUM_LAYERS; ++i) {
        const unsigned short* src_tab = hbf;
        if (i > 0) {
            hvadd_kernel<<<(N_NODES * 16 + 255) / 256, 256, 0, stream>>>(hbf, vnb, batch, gbf);
            src_tab = gbf;
        }
        aggr_kernel<<<N_NODES / 16, 256, 0, stream>>>(src_tab, edges, row_start,
                                                      W_e, b_e, zbf, S1, S2);
        conv_kernel<<<conv_grid, 512, 0, stream>>>(
            zbf, wt1 + (size_t)i * HID * HID, conv_b1 + (size_t)i * HID,
            wt2 + (size_t)i * HID * HID, conv_b2 + (size_t)i * HID,
            z2bf, S1, S2, (i < NUM_LAYERS - 1) ? vn_up : nullptr, NUM_GRAPHS * HID);
        bn_kernel<<<(N_NODES + 127) / 128, 256, 0, stream>>>(z2bf, S1, S2, bn_g + (size_t)i * HID,
                                                             bn_b + (size_t)i * HID, batch, hbf,
                                                             (i < NUM_LAYERS - 1) ? vn_up : pool);
        if (i < NUM_LAYERS - 1)
            vnmlp_kernel<<<NUM_GRAPHS, 128, 0, stream>>>(vn_up, vn_W1, vn_b1, vn_W2, vn_b2,
                                                         vn, vnb);
    }

    cls_kernel<<<NUM_GRAPHS, 128, 0, stream>>>(pool, endpos, cls_W1, cls_b1, cls_W2, cls_b2,
                                               (float*)d_out);
}

// Round 15
// 424.293 us; speedup vs baseline: 1.1942x; 1.1942x over previous
//
#include <hip/hip_runtime.h>

#define N_NODES 50000
#define N_EDGES 800000
#define IN_DIM 64
#define HID 128
#define NUM_LAYERS 4
#define NUM_GRAPHS 128
#define BN_EPS 1e-5f

typedef __attribute__((ext_vector_type(8))) short short8;
typedef __attribute__((ext_vector_type(4))) float f32x4;

__device__ inline unsigned short f2bf(float f) {
    unsigned int u = __float_as_uint(f);
    u += 0x7FFFu + ((u >> 16) & 1u);   // round-to-nearest-even
    return (unsigned short)(u >> 16);
}
__device__ inline float bflo(unsigned int p) { return __uint_as_float(p << 16); }
__device__ inline float bfhi(unsigned int p) { return __uint_as_float(p & 0xFFFF0000u); }
__device__ inline float bfch(const uint4& v, int c) {
    unsigned int p = (&v.x)[c >> 1];
    return (c & 1) ? bfhi(p) : bflo(p);
}

// ---------------- fused preprocessing: hist+rank, endpos, weight prep ----------------
__global__ void prep_kernel(const int* __restrict__ dst, int* __restrict__ cnt,
                            int* __restrict__ rank, const int* __restrict__ batch,
                            int* __restrict__ endpos, const float* __restrict__ W_in,
                            const float* __restrict__ conv_W1,
                            const float* __restrict__ conv_W2,
                            unsigned short* __restrict__ wt_in,
                            unsigned short* __restrict__ wt1,
                            unsigned short* __restrict__ wt2) {
    int tid = threadIdx.x;
    // hist + rank (4 independent atomic chains per thread)
    int base = blockIdx.x * 1024 + tid;
#pragma unroll
    for (int u = 0; u < 4; ++u) {
        int e = base + u * 256;
        if (e < N_EDGES) rank[e] = atomicAdd(&cnt[dst[e]], 1);
    }
    int i = blockIdx.x * 256 + tid;
    // endpos (batch sorted; write only at run boundaries)
    if (i < N_NODES) {
        int b = batch[i];
        int b1 = (i + 1 < N_NODES) ? batch[i + 1] : NUM_GRAPHS;
        for (int g = b; g < b1; ++g) endpos[g] = i + 1;
        if (i == 0)
            for (int g = 0; g < b; ++g) endpos[g] = 0;
    }
    // weight transpose + cvt to bf16
    if (i < 128 * IN_DIM) {
        int c = i >> 6, k = i & 63;
        wt_in[i] = f2bf(W_in[k * HID + c]);
    }
    if (i < 4 * HID * HID) {
        int o = i & (HID * HID - 1);
        int layer = i >> 14;
        int c = o >> 7, k = o & 127;
        wt1[i] = f2bf(conv_W1[layer * HID * HID + k * HID + c]);
        wt2[i] = f2bf(conv_W2[layer * HID * HID + k * HID + c]);
    }
}

// ---------------- 2-stage coalesced exclusive scan over 50000 counters ----------------
#define SCAN_BLOCKS ((N_NODES + 1023) / 1024)   // 49

__global__ __launch_bounds__(1024) void scan1_kernel(const int* __restrict__ cnt,
                                                     int* __restrict__ bsum) {
    __shared__ int ls[1024];
    int t = threadIdx.x;
    int g = blockIdx.x * 1024 + t;
    int v = (g < N_NODES) ? cnt[g] : 0;
    ls[t] = v;
    __syncthreads();
    for (int off = 512; off > 0; off >>= 1) {
        if (t < off) ls[t] += ls[t + off];
        __syncthreads();
    }
    if (t == 0) bsum[blockIdx.x] = ls[0];
}

// scan within block + inline cross-block offset (wave64 reduce over bsum[0..bid))
__global__ __launch_bounds__(1024) void scan3_kernel(const int* __restrict__ cnt,
                                                     const int* __restrict__ bsum,
                                                     int* __restrict__ row_start) {
    __shared__ int ls[1024];
    __shared__ int boffS;
    int t = threadIdx.x;
    if (t < 64) {
        int v2 = (t < blockIdx.x && t < SCAN_BLOCKS) ? bsum[t] : 0;
#pragma unroll
        for (int off = 32; off > 0; off >>= 1) v2 += __shfl_down(v2, off);
        if (t == 0) boffS = v2;
    }
    int g = blockIdx.x * 1024 + t;
    int v = (g < N_NODES) ? cnt[g] : 0;
    ls[t] = v;
    __syncthreads();
    for (int off = 1; off < 1024; off <<= 1) {
        int x = (t >= off) ? ls[t - off] : 0;
        __syncthreads();
        ls[t] += x;
        __syncthreads();
    }
    int excl = ls[t] - v + boffS;
    if (g < N_NODES) {
        row_start[g] = excl;
        if (g == N_NODES - 1) row_start[N_NODES] = excl + v;
    }
}

// atomic-free CSR fill: p = row_start[dst] + rank. Record = {src, ea.x, ea.y, 0} (16B, f32 ea).
__global__ void fill_kernel(const int* __restrict__ src, const int* __restrict__ dst,
                            const float* __restrict__ ea, const int* __restrict__ rank,
                            const int* __restrict__ row_start, int4* __restrict__ edges) {
    int e = blockIdx.x * 256 + threadIdx.x;
    if (e >= N_EDGES) return;
    float2 a = *(const float2*)&ea[2 * e];
    int p = row_start[dst[e]] + rank[e];
    edges[p] = make_int4(src[e], __float_as_int(a.x), __float_as_int(a.y), 0);
}

// gbf[n] = bf16(hbf[n] + vnb[batch[n]])  -- pre-combined gather table for aggr
__global__ void hvadd_kernel(const unsigned short* __restrict__ hbf,
                             const unsigned short* __restrict__ vnb,
                             const int* __restrict__ batch,
                             unsigned short* __restrict__ gbf) {
    int idx = blockIdx.x * 256 + threadIdx.x;   // over N_NODES*16
    int n = idx >> 4;
    if (n >= N_NODES) return;
    int cg = (idx & 15) * 8;
    uint4 h = *(const uint4*)&hbf[(size_t)n * HID + cg];
    uint4 v = *(const uint4*)&vnb[(size_t)batch[n] * HID + cg];
    unsigned int o[4];
#pragma unroll
    for (int p = 0; p < 4; ++p) {
        float lo = bflo((&h.x)[p]) + bflo((&v.x)[p]);
        float hi = bfhi((&h.x)[p]) + bfhi((&v.x)[p]);
        o[p] = (unsigned int)f2bf(lo) | ((unsigned int)f2bf(hi) << 16);
    }
    *(uint4*)&gbf[(size_t)n * HID + cg] = make_uint4(o[0], o[1], o[2], o[3]);
}

// ---------------- edge aggregation (16 threads/node, 8-deep pipeline) ----------------
// z[n] = g[n] + sum_edges relu(g[src] + ea@We + be); bf16 in/out.
// Each thread owns 8 channels across ALL edges of its node (no cross-lane reduce).
__global__ __launch_bounds__(256) void aggr_kernel(const unsigned short* __restrict__ gbf,
                                                   const int4* __restrict__ edges,
                                                   const int* __restrict__ row_start,
                                                   const float* __restrict__ We,
                                                   const float* __restrict__ be,
                                                   unsigned short* __restrict__ zbf,
                                                   float* __restrict__ S1,
                                                   float* __restrict__ S2) {
    int tid = threadIdx.x;
    if (blockIdx.x == 0 && tid < HID) {   // zero BN stat accumulators for this layer
        S1[tid] = 0.f;
        S2[tid] = 0.f;
    }
    int cg = (tid & 15) * 8;               // 8-channel group
    int n = blockIdx.x * 16 + (tid >> 4);  // grid exact: 3125*16 = 50000

    float w0[8], w1[8], bc[8];
    {
        float4 a0 = *(const float4*)&We[cg], a1 = *(const float4*)&We[cg + 4];
        float4 b0 = *(const float4*)&We[HID + cg], b1v = *(const float4*)&We[HID + cg + 4];
        float4 c0 = *(const float4*)&be[cg], c1 = *(const float4*)&be[cg + 4];
        w0[0]=a0.x; w0[1]=a0.y; w0[2]=a0.z; w0[3]=a0.w; w0[4]=a1.x; w0[5]=a1.y; w0[6]=a1.z; w0[7]=a1.w;
        w1[0]=b0.x; w1[1]=b0.y; w1[2]=b0.z; w1[3]=b0.w; w1[4]=b1v.x; w1[5]=b1v.y; w1[6]=b1v.z; w1[7]=b1v.w;
        bc[0]=c0.x; bc[1]=c0.y; bc[2]=c0.z; bc[3]=c0.w; bc[4]=c1.x; bc[5]=c1.y; bc[6]=c1.z; bc[7]=c1.w;
    }

    uint4 hs = *(const uint4*)&gbf[(size_t)n * HID + cg];   // self term (issued early)
    int jb = row_start[n], je = row_start[n + 1];
    float acc[8];
#pragma unroll
    for (int c = 0; c < 8; ++c) acc[c] = 0.f;

    int j = jb;
    for (; j + 8 <= je; j += 8) {
        int4 q[8];
        uint4 hq[8];
#pragma unroll
        for (int u = 0; u < 8; ++u) q[u] = edges[j + u];
#pragma unroll
        for (int u = 0; u < 8; ++u) hq[u] = *(const uint4*)&gbf[(size_t)q[u].x * HID + cg];
#pragma unroll
        for (int u = 0; u < 8; ++u) {
            float ex = __int_as_float(q[u].y), ey = __int_as_float(q[u].z);
#pragma unroll
            for (int c = 0; c < 8; ++c)
                acc[c] += fmaxf(bfch(hq[u], c) + fmaf(ex, w0[c], fmaf(ey, w1[c], bc[c])), 0.f);
        }
    }
    if (j + 4 <= je) {
        int4 q[4];
        uint4 hq[4];
#pragma unroll
        for (int u = 0; u < 4; ++u) q[u] = edges[j + u];
#pragma unroll
        for (int u = 0; u < 4; ++u) hq[u] = *(const uint4*)&gbf[(size_t)q[u].x * HID + cg];
#pragma unroll
        for (int u = 0; u < 4; ++u) {
            float ex = __int_as_float(q[u].y), ey = __int_as_float(q[u].z);
#pragma unroll
            for (int c = 0; c < 8; ++c)
                acc[c] += fmaxf(bfch(hq[u], c) + fmaf(ex, w0[c], fmaf(ey, w1[c], bc[c])), 0.f);
        }
        j += 4;
    }
    for (; j < je; ++j) {
        int4 q = edges[j];
        uint4 hq = *(const uint4*)&gbf[(size_t)q.x * HID + cg];
        float ex = __int_as_float(q.y), ey = __int_as_float(q.z);
#pragma unroll
        for (int c = 0; c < 8; ++c)
            acc[c] += fmaxf(bfch(hq, c) + fmaf(ex, w0[c], fmaf(ey, w1[c], bc[c])), 0.f);
    }

    unsigned int o[4];
#pragma unroll
    for (int p = 0; p < 4; ++p)
        o[p] = (unsigned int)f2bf(bflo((&hs.x)[p]) + acc[2 * p]) |
               ((unsigned int)f2bf(bfhi((&hs.x)[p]) + acc[2 * p + 1]) << 16);
    *(uint4*)&zbf[(size_t)n * HID + cg] = make_uint4(o[0], o[1], o[2], o[3]);
}

// ---------------- input GEMM (bf16 MFMA): hbf = bf16(x @ W_in + b_in) ----------------
__global__ __launch_bounds__(256) void ingemm_kernel(const float* __restrict__ A,
                                                     const unsigned short* __restrict__ Wt,
                                                     const float* __restrict__ bias,
                                                     unsigned short* __restrict__ outbf) {
    constexpr int KD = IN_DIM;
    __shared__ unsigned short aS[64 * KD];
    __shared__ unsigned short wS[128 * KD];
    int tid = threadIdx.x;
    int row0 = blockIdx.x * 64;

#pragma unroll
    for (int it = 0; it < (64 * KD) / (256 * 4); ++it) {
        int idx = it * 1024 + tid * 4;
        int r = idx / KD, k = idx % KD;
        int grow = row0 + r;
        float4 v = (grow < N_NODES) ? *(const float4*)&A[(size_t)grow * KD + k]
                                    : make_float4(0.f, 0.f, 0.f, 0.f);
        unsigned int d0 = (unsigned int)f2bf(v.x) | ((unsigned int)f2bf(v.y) << 16);
        unsigned int d1 = (unsigned int)f2bf(v.z) | ((unsigned int)f2bf(v.w) << 16);
        unsigned int byte = (unsigned int)(idx * 2) ^ (unsigned int)((r & 7) << 4);
        *(uint2*)((char*)aS + byte) = make_uint2(d0, d1);
    }
#pragma unroll
    for (int it = 0; it < (128 * KD) / (256 * 8); ++it) {
        int idx = it * 2048 + tid * 8;
        int c = idx / KD;
        uint4 v = *(const uint4*)&Wt[idx];
        unsigned int byte = (unsigned int)(idx * 2) ^ (unsigned int)((c & 7) << 4);
        *(uint4*)((char*)wS + byte) = v;
    }
    __syncthreads();

    int w = tid >> 6, l = tid & 63;
    int wr = w >> 1, wc = w & 1, lr = l & 15, kq = (l >> 4) * 8;
    f32x4 acc[2][4];
#pragma unroll
    for (int r = 0; r < 2; ++r)
#pragma unroll
        for (int t = 0; t < 4; ++t) acc[r][t] = (f32x4){0.f, 0.f, 0.f, 0.f};

#pragma unroll
    for (int sstep = 0; sstep < KD / 32; ++sstep) {
        int k0 = sstep * 32 + kq;
        int ar0 = 32 * wr + lr, ar1 = ar0 + 16;
        short8 af0 = *(short8*)((char*)aS + ((unsigned int)((ar0 * KD + k0) * 2) ^
                                            (unsigned int)((ar0 & 7) << 4)));
        short8 af1 = *(short8*)((char*)aS + ((unsigned int)((ar1 * KD + k0) * 2) ^
                                            (unsigned int)((ar1 & 7) << 4)));
#pragma unroll
        for (int t = 0; t < 4; ++t) {
            int col = 64 * wc + 16 * t + lr;
            short8 bf = *(short8*)((char*)wS + ((unsigned int)((col * KD + k0) * 2) ^
                                               (unsigned int)((col & 7) << 4)));
            acc[0][t] = __builtin_amdgcn_mfma_f32_16x16x32_bf16(af0, bf, acc[0][t], 0, 0, 0);
            acc[1][t] = __builtin_amdgcn_mfma_f32_16x16x32_bf16(af1, bf, acc[1][t], 0, 0, 0);
        }
    }
#pragma unroll
    for (int r = 0; r < 2; ++r) {
        int rbase = row0 + 32 * wr + 16 * r + (l >> 4) * 4;
#pragma unroll
        for (int t = 0; t < 4; ++t) {
            int col = 64 * wc + 16 * t + lr;
            float b = bias[col];
#pragma unroll
            for (int q = 0; q < 4; ++q) {
                int grow = rbase + q;
                if (grow < N_NODES) outbf[(size_t)grow * HID + col] = f2bf(acc[r][t][q] + b);
            }
        }
    }
}

// ---------------- fused conv MLP: z2 = relu(z@W1+b1)@W2+b2, + BN stats ----------------
// 128x128 tile, 512 threads = 8 waves (2x4). y lives in LDS (reuses z tile).
// BN stats shuffle-reduced across the 4 same-column lanes before LDS atomics.
__global__ __launch_bounds__(512) void conv_kernel(const unsigned short* __restrict__ zbf,
                                                   const unsigned short* __restrict__ Wt1,
                                                   const float* __restrict__ b1,
                                                   const unsigned short* __restrict__ Wt2,
                                                   const float* __restrict__ b2,
                                                   unsigned short* __restrict__ z2bf,
                                                   float* __restrict__ S1,
                                                   float* __restrict__ S2,
                                                   float* __restrict__ zinit, int zinit_n) {
    constexpr int KD = HID;
    __shared__ unsigned short aS[128 * KD];   // z tile, then y tile (32 KB)
    __shared__ unsigned short wS[128 * KD];   // W1, then W2 (32 KB)
    __shared__ float sh1[HID], sh2[HID];
    int tid = threadIdx.x;
    if (zinit && blockIdx.x == 0)
        for (int i = tid; i < zinit_n; i += 512) zinit[i] = 0.f;
    if (tid < HID) { sh1[tid] = 0.f; sh2[tid] = 0.f; }

    int row0 = blockIdx.x * 128;

#pragma unroll
    for (int it = 0; it < 4; ++it) {          // 128*128/(512*8)
        int idx = it * 4096 + tid * 8;
        int r = idx >> 7;
        int grow = row0 + r;
        uint4 v = (grow < N_NODES) ? *(const uint4*)&zbf[(size_t)grow * HID + (idx & 127)]
                                   : make_uint4(0u, 0u, 0u, 0u);
        unsigned int byte = (unsigned int)(idx * 2) ^ (unsigned int)((r & 7) << 4);
        *(uint4*)((char*)aS + byte) = v;
    }
#pragma unroll
    for (int it = 0; it < 4; ++it) {
        int idx = it * 4096 + tid * 8;
        int c = idx >> 7;
        uint4 v = *(const uint4*)&Wt1[idx];
        unsigned int byte = (unsigned int)(idx * 2) ^ (unsigned int)((c & 7) << 4);
        *(uint4*)((char*)wS + byte) = v;
    }
    __syncthreads();

    int w = tid >> 6, l = tid & 63;
    int wr = w >> 2, wc = w & 3;       // 2x4 wave grid: 64 rows x 32 cols per wave
    int lr = l & 15, kq = (l >> 4) * 8;

    f32x4 acc[4][2];
#pragma unroll
    for (int rt = 0; rt < 4; ++rt)
#pragma unroll
        for (int ct = 0; ct < 2; ++ct) acc[rt][ct] = (f32x4){0.f, 0.f, 0.f, 0.f};

#pragma unroll
    for (int sstep = 0; sstep < 4; ++sstep) {
        int k0 = sstep * 32 + kq;
        short8 af[4];
#pragma unroll
        for (int rt = 0; rt < 4; ++rt) {
            int ar = 64 * wr + 16 * rt + lr;
            af[rt] = *(short8*)((char*)aS + ((unsigned int)((ar * KD + k0) * 2) ^
                                            (unsigned int)((ar & 7) << 4)));
        }
#pragma unroll
        for (int ct = 0; ct < 2; ++ct) {
            int col = 32 * wc + 16 * ct + lr;
            short8 bf = *(short8*)((char*)wS + ((unsigned int)((col * KD + k0) * 2) ^
                                               (unsigned int)((col & 7) << 4)));
#pragma unroll
            for (int rt = 0; rt < 4; ++rt)
                acc[rt][ct] = __builtin_amdgcn_mfma_f32_16x16x32_bf16(af[rt], bf, acc[rt][ct], 0, 0, 0);
        }
    }
    __syncthreads();   // everyone done reading aS (z) and wS (W1)

    // y = relu(acc + b1) -> aS (bf16, swizzled); stage W2 -> wS
#pragma unroll
    for (int rt = 0; rt < 4; ++rt) {
        int lrow0 = 64 * wr + 16 * rt + (l >> 4) * 4;
#pragma unroll
        for (int ct = 0; ct < 2; ++ct) {
            int col = 32 * wc + 16 * ct + lr;
            float b = b1[col];
#pragma unroll
            for (int q = 0; q < 4; ++q) {
                int lrow = lrow0 + q;
                float v = fmaxf(acc[rt][ct][q] + b, 0.f);
                unsigned int byte = (unsigned int)((lrow * KD + col) * 2) ^
                                    (unsigned int)((lrow & 7) << 4);
                *(unsigned short*)((char*)aS + byte) = f2bf(v);
            }
        }
    }
#pragma unroll
    for (int it = 0; it < 4; ++it) {
        int idx = it * 4096 + tid * 8;
        int c = idx >> 7;
        uint4 v = *(const uint4*)&Wt2[idx];
        unsigned int byte = (unsigned int)(idx * 2) ^ (unsigned int)((c & 7) << 4);
        *(uint4*)((char*)wS + byte) = v;
    }
    __syncthreads();

    f32x4 acc2[4][2];
#pragma unroll
    for (int rt = 0; rt < 4; ++rt)
#pragma unroll
        for (int ct = 0; ct < 2; ++ct) acc2[rt][ct] = (f32x4){0.f, 0.f, 0.f, 0.f};

#pragma unroll
    for (int sstep = 0; sstep < 4; ++sstep) {
        int k0 = sstep * 32 + kq;
        short8 af[4];
#pragma unroll
        for (int rt = 0; rt < 4; ++rt) {
            int ar = 64 * wr + 16 * rt + lr;
            af[rt] = *(short8*)((char*)aS + ((unsigned int)((ar * KD + k0) * 2) ^
                                            (unsigned int)((ar & 7) << 4)));
        }
#pragma unroll
        for (int ct = 0; ct < 2; ++ct) {
            int col = 32 * wc + 16 * ct + lr;
            short8 bf = *(short8*)((char*)wS + ((unsigned int)((col * KD + k0) * 2) ^
                                               (unsigned int)((col & 7) << 4)));
#pragma unroll
            for (int rt = 0; rt < 4; ++rt)
                acc2[rt][ct] = __builtin_amdgcn_mfma_f32_16x16x32_bf16(af[rt], bf, acc2[rt][ct], 0, 0, 0);
        }
    }

    // epilogue: z2 = acc2 + b2 -> z2bf (bf16) + BN stats (register acc + shuffle reduce)
    float s1v[2] = {0.f, 0.f}, s2v[2] = {0.f, 0.f};
#pragma unroll
    for (int rt = 0; rt < 4; ++rt) {
        int rbase = row0 + 64 * wr + 16 * rt + (l >> 4) * 4;
#pragma unroll
        for (int ct = 0; ct < 2; ++ct) {
            int col = 32 * wc + 16 * ct + lr;
            float b = b2[col];
#pragma unroll
            for (int q = 0; q < 4; ++q) {
                int grow = rbase + q;
                if (grow < N_NODES) {
                    float v = acc2[rt][ct][q] + b;
                    z2bf[(size_t)grow * HID + col] = f2bf(v);
                    s1v[ct] += v;
                    s2v[ct] += v * v;
                }
            }
        }
    }
#pragma unroll
    for (int ct = 0; ct < 2; ++ct) {
        float a = s1v[ct], bsum2 = s2v[ct];
        a += __shfl_xor(a, 16); a += __shfl_xor(a, 32);
        bsum2 += __shfl_xor(bsum2, 16); bsum2 += __shfl_xor(bsum2, 32);
        if ((l >> 4) == 0) {
            int col = 32 * wc + 16 * ct + lr;
            atomicAdd(&sh1[col], a);
            atomicAdd(&sh2[col], bsum2);
        }
    }
    __syncthreads();
    if (tid < HID) {
        atomicAdd(&S1[tid], sh1[tid]);
        atomicAdd(&S2[tid], sh2[tid]);
    }
}

// ---------------- BN apply + relu -> hbf (bf16) + segment-sum into vn_up/pool ----------------
__global__ __launch_bounds__(256) void bn_kernel(const unsigned short* __restrict__ z2bf,
                                                 const float* __restrict__ S1,
                                                 const float* __restrict__ S2,
                                                 const float* __restrict__ gma,
                                                 const float* __restrict__ bta,
                                                 const int* __restrict__ batch,
                                                 unsigned short* __restrict__ hbf,
                                                 float* __restrict__ up) {
    int tid = threadIdx.x;
    int cg = (tid & 31) * 4;
    int n0 = (blockIdx.x * 8 + (tid >> 5)) * 16;
    const float inv = 1.f / (float)N_NODES;
    float4 s1 = *(const float4*)&S1[cg];
    float4 s2 = *(const float4*)&S2[cg];
    float4 g4 = *(const float4*)&gma[cg];
    float4 b4 = *(const float4*)&bta[cg];
    float mux = s1.x * inv, muy = s1.y * inv, muz = s1.z * inv, muw = s1.w * inv;
    float gmx = g4.x * rsqrtf(s2.x * inv - mux * mux + BN_EPS);
    float gmy = g4.y * rsqrtf(s2.y * inv - muy * muy + BN_EPS);
    float gmz = g4.z * rsqrtf(s2.z * inv - muz * muz + BN_EPS);
    float gmw = g4.w * rsqrtf(s2.w * inv - muw * muw + BN_EPS);

    float4 acc = make_float4(0.f, 0.f, 0.f, 0.f);
    int gcur = -1;
    for (int i = 0; i < 16; ++i) {
        int n = n0 + i;
        if (n >= N_NODES) break;
        uint2 zv = *(const uint2*)&z2bf[(size_t)n * HID + cg];
        float4 hn;
        hn.x = fmaxf(fmaf(bflo(zv.x) - mux, gmx, b4.x), 0.f);
        hn.y = fmaxf(fmaf(bfhi(zv.x) - muy, gmy, b4.y), 0.f);
        hn.z = fmaxf(fmaf(bflo(zv.y) - muz, gmz, b4.z), 0.f);
        hn.w = fmaxf(fmaf(bfhi(zv.y) - muw, gmw, b4.w), 0.f);
        uint2 pk;
        pk.x = (unsigned int)f2bf(hn.x) | ((unsigned int)f2bf(hn.y) << 16);
        pk.y = (unsigned int)f2bf(hn.z) | ((unsigned int)f2bf(hn.w) << 16);
        *(uint2*)&hbf[(size_t)n * HID + cg] = pk;
        int gb = batch[n];
        if (gb != gcur) {
            if (gcur >= 0) {
                atomicAdd(&up[gcur * HID + cg + 0], acc.x);
                atomicAdd(&up[gcur * HID + cg + 1], acc.y);
                atomicAdd(&up[gcur * HID + cg + 2], acc.z);
                atomicAdd(&up[gcur * HID + cg + 3], acc.w);
            }
            acc = make_float4(0.f, 0.f, 0.f, 0.f);
            gcur = gb;
        }
        acc.x += hn.x; acc.y += hn.y; acc.z += hn.z; acc.w += hn.w;
    }
    if (gcur >= 0) {
        atomicAdd(&up[gcur * HID + cg + 0], acc.x);
        atomicAdd(&up[gcur * HID + cg + 1], acc.y);
        atomicAdd(&up[gcur * HID + cg + 2], acc.z);
        atomicAdd(&up[gcur * HID + cg + 3], acc.w);
    }
}

// ---------------- virtual-node MLP: vn += relu(up@W1+b1)@W2+b2; also bf16 copy ----------------
__global__ __launch_bounds__(128) void vnmlp_kernel(const float* __restrict__ up,
                                                    const float* __restrict__ W1,
                                                    const float* __restrict__ b1,
                                                    const float* __restrict__ W2,
                                                    const float* __restrict__ b2,
                                                    float* __restrict__ vn,
                                                    unsigned short* __restrict__ vnb) {
    __shared__ float t[HID];
    int g = blockIdx.x, c = threadIdx.x;
    float s = b1[c];
#pragma unroll 8
    for (int k = 0; k < HID; ++k) s = fmaf(up[g * HID + k], W1[k * HID + c], s);
    t[c] = fmaxf(s, 0.f);
    __syncthreads();
    float s2 = b2[c];
#pragma unroll 8
    for (int k = 0; k < HID; ++k) s2 = fmaf(t[k], W2[k * HID + c], s2);
    float nv = vn[g * HID + c] + s2;
    vn[g * HID + c] = nv;
    vnb[g * HID + c] = f2bf(nv);
}

// ---------------- classifier: logits[g] ----------------
__global__ __launch_bounds__(128) void cls_kernel(const float* __restrict__ pool,
                                                  const int* __restrict__ endpos,
                                                  const float* __restrict__ W1,
                                                  const float* __restrict__ b1,
                                                  const float* __restrict__ W2,
                                                  const float* __restrict__ b2,
                                                  float* __restrict__ out) {
    __shared__ float t[HID];
    __shared__ float red[HID];
    int g = blockIdx.x, c = threadIdx.x;
    int cnt = endpos[g] - (g > 0 ? endpos[g - 1] : 0);
    float cntf = fmaxf((float)cnt, 1.f);
    t[c] = pool[g * HID + c] / cntf;
    __syncthreads();
    float s = b1[c];
#pragma unroll 8
    for (int k = 0; k < HID; ++k) s = fmaf(t[k], W1[k * HID + c], s);
    float y = fmaxf(s, 0.f);
    red[c] = y * W2[c];
    __syncthreads();
    for (int off = 64; off > 0; off >>= 1) {
        if (c < off) red[c] += red[c + off];
        __syncthreads();
    }
    if (c == 0) out[g] = red[0] + b2[0];
}

// ---------------- host-side orchestration ----------------
extern "C" void kernel_launch(void* const* d_in, const int* in_sizes, int n_in,
                              void* d_out, int out_size, void* d_ws, size_t ws_size,
                              hipStream_t stream) {
    const float* x        = (const float*)d_in[0];
    const float* edge_attr= (const float*)d_in[1];
    const int*   edge_idx = (const int*)d_in[2];
    const int*   batch    = (const int*)d_in[3];
    const float* W_in     = (const float*)d_in[4];
    const float* b_in     = (const float*)d_in[5];
    const float* W_e      = (const float*)d_in[6];
    const float* b_e      = (const float*)d_in[7];
    const float* conv_W1  = (const float*)d_in[8];
    const float* conv_b1  = (const float*)d_in[9];
    const float* conv_W2  = (const float*)d_in[10];
    const float* conv_b2  = (const float*)d_in[11];
    const float* bn_g     = (const float*)d_in[12];
    const float* bn_b     = (const float*)d_in[13];
    const float* vn_W1    = (const float*)d_in[14];
    const float* vn_b1    = (const float*)d_in[15];
    const float* vn_W2    = (const float*)d_in[16];
    const float* vn_b2    = (const float*)d_in[17];
    const float* cls_W1   = (const float*)d_in[18];
    const float* cls_b1   = (const float*)d_in[19];
    const float* cls_W2   = (const float*)d_in[20];
    const float* cls_b2   = (const float*)d_in[21];

    char* ws = (char*)d_ws;
    size_t off = 0;
    auto alloc = [&](size_t bytes) -> void* {
        void* p = ws + off;
        off = (off + bytes + 255) & ~(size_t)255;
        return p;
    };
    unsigned short* z2bf = (unsigned short*)alloc((size_t)N_NODES * HID * 2);
    unsigned short* hbf = (unsigned short*)alloc((size_t)N_NODES * HID * 2);
    unsigned short* gbf = (unsigned short*)alloc((size_t)N_NODES * HID * 2);
    unsigned short* zbf = (unsigned short*)alloc((size_t)N_NODES * HID * 2);
    size_t zero_begin = off;
    int*   cnt    = (int*)alloc((size_t)N_NODES * 4);
    float* vn     = (float*)alloc((size_t)NUM_GRAPHS * HID * 4);
    unsigned short* vnb = (unsigned short*)alloc((size_t)NUM_GRAPHS * HID * 2);
    float* pool   = (float*)alloc((size_t)NUM_GRAPHS * HID * 4);
    size_t zero_end = off;
    int*    endpos    = (int*)alloc((size_t)NUM_GRAPHS * 4);
    int*    row_start = (int*)alloc((size_t)(N_NODES + 1) * 4);
    int*    rank      = (int*)alloc((size_t)N_EDGES * 4);
    int4*   edges     = (int4*)alloc((size_t)N_EDGES * 16);
    float*  vn_up     = (float*)alloc((size_t)NUM_GRAPHS * HID * 4);
    float*  S1        = (float*)alloc((size_t)HID * 4);
    float*  S2        = (float*)alloc((size_t)HID * 4);
    int*    bsum      = (int*)alloc((size_t)SCAN_BLOCKS * 4);
    unsigned short* wt_in = (unsigned short*)alloc((size_t)HID * IN_DIM * 2);
    unsigned short* wt1   = (unsigned short*)alloc((size_t)NUM_LAYERS * HID * HID * 2);
    unsigned short* wt2   = (unsigned short*)alloc((size_t)NUM_LAYERS * HID * HID * 2);
    (void)ws_size; (void)in_sizes; (void)n_in; (void)out_size;

    const int* srcp = edge_idx;
    const int* dstp = edge_idx + N_EDGES;

    hipMemsetAsync(ws + zero_begin, 0, zero_end - zero_begin, stream);
    prep_kernel<<<(N_EDGES + 1023) / 1024, 256, 0, stream>>>(dstp, cnt, rank, batch, endpos,
                                                             W_in, conv_W1, conv_W2,
                                                             wt_in, wt1, wt2);
    scan1_kernel<<<SCAN_BLOCKS, 1024, 0, stream>>>(cnt, bsum);
    scan3_kernel<<<SCAN_BLOCKS, 1024, 0, stream>>>(cnt, bsum, row_start);
    fill_kernel<<<(N_EDGES + 255) / 256, 256, 0, stream>>>(srcp, dstp, edge_attr, rank,
                                                           row_start, edges);

    ingemm_kernel<<<(N_NODES + 63) / 64, 256, 0, stream>>>(x, wt_in, b_in, hbf);

    const int conv_grid = (N_NODES + 127) / 128;   // 391
    for (int i = 0; i < NUM_LAYERS; ++i) {
        const unsigned short* src_tab = hbf;
        if (i > 0) {
            hvadd_kernel<<<(N_NODES * 16 + 255) / 256, 256, 0, stream>>>(hbf, vnb, batch, gbf);
            src_tab = gbf;
        }
        aggr_kernel<<<N_NODES / 16, 256, 0, stream>>>(src_tab, edges, row_start,
                                                      W_e, b_e, zbf, S1, S2);
        conv_kernel<<<conv_grid, 512, 0, stream>>>(
            zbf, wt1 + (size_t)i * HID * HID, conv_b1 + (size_t)i * HID,
            wt2 + (size_t)i * HID * HID, conv_b2 + (size_t)i * HID,
            z2bf, S1, S2, (i < NUM_LAYERS - 1) ? vn_up : nullptr, NUM_GRAPHS * HID);
        bn_kernel<<<(N_NODES + 127) / 128, 256, 0, stream>>>(z2bf, S1, S2, bn_g + (size_t)i * HID,
                                                             bn_b + (size_t)i * HID, batch, hbf,
                                                             (i < NUM_LAYERS - 1) ? vn_up : pool);
        if (i < NUM_LAYERS - 1)
            vnmlp_kernel<<<NUM_GRAPHS, 128, 0, stream>>>(vn_up, vn_W1, vn_b1, vn_W2, vn_b2,
                                                         vn, vnb);
    }

    cls_kernel<<<NUM_GRAPHS, 128, 0, stream>>>(pool, endpos, cls_W1, cls_b1, cls_W2, cls_b2,
                                               (float*)d_out);
}

// Round 17
// 422.972 us; speedup vs baseline: 1.1979x; 1.0031x over previous
//
#include <hip/hip_runtime.h>
#include <hip/hip_fp16.h>

#define N_NODES 50000
#define N_EDGES 800000
#define IN_DIM 64
#define HID 128
#define NUM_LAYERS 4
#define NUM_GRAPHS 128
#define BN_EPS 1e-5f

typedef __attribute__((ext_vector_type(8))) short short8;
typedef __attribute__((ext_vector_type(4))) float f32x4;

__device__ inline unsigned short f2bf(float f) {
    unsigned int u = __float_as_uint(f);
    u += 0x7FFFu + ((u >> 16) & 1u);   // round-to-nearest-even
    return (unsigned short)(u >> 16);
}
__device__ inline float bflo(unsigned int p) { return __uint_as_float(p << 16); }
__device__ inline float bfhi(unsigned int p) { return __uint_as_float(p & 0xFFFF0000u); }
__device__ inline unsigned short f2h_bits(float f) {
    __half h = __float2half(f);
    return *(unsigned short*)&h;
}
__device__ inline unsigned int h2bits(__half2 h) { return *(unsigned int*)&h; }
__device__ inline __half2 bits2h2(unsigned int u) { return *(__half2*)&u; }
// packed f16 max via ISA (header lacks __hmax2 on ROCm 7.2)
__device__ inline __half2 pkmax2(__half2 a, __half2 b) {
    unsigned int r, ua = h2bits(a), ub = h2bits(b);
    asm("v_pk_max_f16 %0, %1, %2" : "=v"(r) : "v"(ua), "v"(ub));
    return bits2h2(r);
}

// ---------------- fused preprocessing: hist+rank, endpos, weight prep ----------------
__global__ void prep_kernel(const int* __restrict__ dst, int* __restrict__ cnt,
                            int* __restrict__ rank, const int* __restrict__ batch,
                            int* __restrict__ endpos, const float* __restrict__ W_in,
                            const float* __restrict__ conv_W1,
                            const float* __restrict__ conv_W2,
                            unsigned short* __restrict__ wt_in,
                            unsigned short* __restrict__ wt1,
                            unsigned short* __restrict__ wt2) {
    int tid = threadIdx.x;
    int base = blockIdx.x * 1024 + tid;
#pragma unroll
    for (int u = 0; u < 4; ++u) {
        int e = base + u * 256;
        if (e < N_EDGES) rank[e] = atomicAdd(&cnt[dst[e]], 1);
    }
    int i = blockIdx.x * 256 + tid;
    if (i < N_NODES) {
        int b = batch[i];
        int b1 = (i + 1 < N_NODES) ? batch[i + 1] : NUM_GRAPHS;
        for (int g = b; g < b1; ++g) endpos[g] = i + 1;
        if (i == 0)
            for (int g = 0; g < b; ++g) endpos[g] = 0;
    }
    if (i < 128 * IN_DIM) {
        int c = i >> 6, k = i & 63;
        wt_in[i] = f2bf(W_in[k * HID + c]);
    }
    if (i < 4 * HID * HID) {
        int o = i & (HID * HID - 1);
        int layer = i >> 14;
        int c = o >> 7, k = o & 127;
        wt1[i] = f2bf(conv_W1[layer * HID * HID + k * HID + c]);
        wt2[i] = f2bf(conv_W2[layer * HID * HID + k * HID + c]);
    }
}

// ---------------- 2-stage coalesced exclusive scan over 50000 counters ----------------
#define SCAN_BLOCKS ((N_NODES + 1023) / 1024)   // 49

__global__ __launch_bounds__(1024) void scan1_kernel(const int* __restrict__ cnt,
                                                     int* __restrict__ bsum) {
    __shared__ int ls[1024];
    int t = threadIdx.x;
    int g = blockIdx.x * 1024 + t;
    int v = (g < N_NODES) ? cnt[g] : 0;
    ls[t] = v;
    __syncthreads();
    for (int off = 512; off > 0; off >>= 1) {
        if (t < off) ls[t] += ls[t + off];
        __syncthreads();
    }
    if (t == 0) bsum[blockIdx.x] = ls[0];
}

__global__ __launch_bounds__(1024) void scan3_kernel(const int* __restrict__ cnt,
                                                     const int* __restrict__ bsum,
                                                     int* __restrict__ row_start) {
    __shared__ int ls[1024];
    __shared__ int boffS;
    int t = threadIdx.x;
    if (t < 64) {
        int v2 = (t < blockIdx.x && t < SCAN_BLOCKS) ? bsum[t] : 0;
#pragma unroll
        for (int off = 32; off > 0; off >>= 1) v2 += __shfl_down(v2, off);
        if (t == 0) boffS = v2;
    }
    int g = blockIdx.x * 1024 + t;
    int v = (g < N_NODES) ? cnt[g] : 0;
    ls[t] = v;
    __syncthreads();
    for (int off = 1; off < 1024; off <<= 1) {
        int x = (t >= off) ? ls[t - off] : 0;
        __syncthreads();
        ls[t] += x;
        __syncthreads();
    }
    int excl = ls[t] - v + boffS;
    if (g < N_NODES) {
        row_start[g] = excl;
        if (g == N_NODES - 1) row_start[N_NODES] = excl + v;
    }
}

// atomic-free CSR fill: p = row_start[dst] + rank. Record = {src, ea.x, ea.y, 0} (16B, f32 ea).
__global__ void fill_kernel(const int* __restrict__ src, const int* __restrict__ dst,
                            const float* __restrict__ ea, const int* __restrict__ rank,
                            const int* __restrict__ row_start, int4* __restrict__ edges) {
    int e = blockIdx.x * 256 + threadIdx.x;
    if (e >= N_EDGES) return;
    float2 a = *(const float2*)&ea[2 * e];
    int p = row_start[dst[e]] + rank[e];
    edges[p] = make_int4(src[e], __float_as_int(a.x), __float_as_int(a.y), 0);
}

// gh[n] = f16(hh[n] + vnh[batch[n]])  -- pre-combined f16 gather table (packed adds)
__global__ void hvadd_kernel(const unsigned short* __restrict__ hh,
                             const unsigned short* __restrict__ vnh,
                             const int* __restrict__ batch,
                             unsigned short* __restrict__ gh) {
    int idx = blockIdx.x * 256 + threadIdx.x;   // over N_NODES*16
    int n = idx >> 4;
    if (n >= N_NODES) return;
    int cg = (idx & 15) * 8;
    uint4 h = *(const uint4*)&hh[(size_t)n * HID + cg];
    uint4 v = *(const uint4*)&vnh[(size_t)batch[n] * HID + cg];
    unsigned int o[4];
#pragma unroll
    for (int p = 0; p < 4; ++p)
        o[p] = h2bits(__hadd2(bits2h2((&h.x)[p]), bits2h2((&v.x)[p])));
    *(uint4*)&gh[(size_t)n * HID + cg] = make_uint4(o[0], o[1], o[2], o[3]);
}

// ---------------- edge aggregation (16 threads/node, 8-deep, packed f16 math) ----------------
// z[n] = g[n] + sum_edges relu(g[src] + ea@We + be); f16 gather table, bf16 z out.
__global__ __launch_bounds__(256) void aggr_kernel(const unsigned short* __restrict__ gh,
                                                   const int4* __restrict__ edges,
                                                   const int* __restrict__ row_start,
                                                   const float* __restrict__ We,
                                                   const float* __restrict__ be,
                                                   unsigned short* __restrict__ zbf,
                                                   float* __restrict__ S1,
                                                   float* __restrict__ S2) {
    int tid = threadIdx.x;
    if (blockIdx.x == 0 && tid < HID) {   // zero BN stat accumulators for this layer
        S1[tid] = 0.f;
        S2[tid] = 0.f;
    }
    int cg = (tid & 15) * 8;               // 8-channel group
    int n = blockIdx.x * 16 + (tid >> 4);  // grid exact: 3125*16 = 50000

    __half2 w0p[4], w1p[4], bcp[4];
    {
        float4 a0 = *(const float4*)&We[cg], a1 = *(const float4*)&We[cg + 4];
        float4 b0 = *(const float4*)&We[HID + cg], b1v = *(const float4*)&We[HID + cg + 4];
        float4 c0 = *(const float4*)&be[cg], c1 = *(const float4*)&be[cg + 4];
        w0p[0] = __floats2half2_rn(a0.x, a0.y); w0p[1] = __floats2half2_rn(a0.z, a0.w);
        w0p[2] = __floats2half2_rn(a1.x, a1.y); w0p[3] = __floats2half2_rn(a1.z, a1.w);
        w1p[0] = __floats2half2_rn(b0.x, b0.y); w1p[1] = __floats2half2_rn(b0.z, b0.w);
        w1p[2] = __floats2half2_rn(b1v.x, b1v.y); w1p[3] = __floats2half2_rn(b1v.z, b1v.w);
        bcp[0] = __floats2half2_rn(c0.x, c0.y); bcp[1] = __floats2half2_rn(c0.z, c0.w);
        bcp[2] = __floats2half2_rn(c1.x, c1.y); bcp[3] = __floats2half2_rn(c1.z, c1.w);
    }
    const __half2 zero2 = __floats2half2_rn(0.f, 0.f);

    uint4 hs = *(const uint4*)&gh[(size_t)n * HID + cg];   // self term (issued early)
    int jb = row_start[n], je = row_start[n + 1];
    float acc[8];
#pragma unroll
    for (int c = 0; c < 8; ++c) acc[c] = 0.f;

    int j = jb;
    for (; j + 8 <= je; j += 8) {
        int4 q[8];
        uint4 hq[8];
#pragma unroll
        for (int u = 0; u < 8; ++u) q[u] = edges[j + u];
#pragma unroll
        for (int u = 0; u < 8; ++u) hq[u] = *(const uint4*)&gh[(size_t)q[u].x * HID + cg];
#pragma unroll
        for (int u = 0; u < 8; ++u) {
            __half2 exh = __float2half2_rn(__int_as_float(q[u].y));
            __half2 eyh = __float2half2_rn(__int_as_float(q[u].z));
#pragma unroll
            for (int p = 0; p < 4; ++p) {
                __half2 m = __hfma2(exh, w0p[p], __hfma2(eyh, w1p[p], bcp[p]));
                __half2 t = pkmax2(__hadd2(bits2h2((&hq[u].x)[p]), m), zero2);
                float2 tf = __half22float2(t);
                acc[2 * p] += tf.x;
                acc[2 * p + 1] += tf.y;
            }
        }
    }
    if (j + 4 <= je) {
        int4 q[4];
        uint4 hq[4];
#pragma unroll
        for (int u = 0; u < 4; ++u) q[u] = edges[j + u];
#pragma unroll
        for (int u = 0; u < 4; ++u) hq[u] = *(const uint4*)&gh[(size_t)q[u].x * HID + cg];
#pragma unroll
        for (int u = 0; u < 4; ++u) {
            __half2 exh = __float2half2_rn(__int_as_float(q[u].y));
            __half2 eyh = __float2half2_rn(__int_as_float(q[u].z));
#pragma unroll
            for (int p = 0; p < 4; ++p) {
                __half2 m = __hfma2(exh, w0p[p], __hfma2(eyh, w1p[p], bcp[p]));
                __half2 t = pkmax2(__hadd2(bits2h2((&hq[u].x)[p]), m), zero2);
                float2 tf = __half22float2(t);
                acc[2 * p] += tf.x;
                acc[2 * p + 1] += tf.y;
            }
        }
        j += 4;
    }
    for (; j < je; ++j) {
        int4 q = edges[j];
        uint4 hq = *(const uint4*)&gh[(size_t)q.x * HID + cg];
        __half2 exh = __float2half2_rn(__int_as_float(q.y));
        __half2 eyh = __float2half2_rn(__int_as_float(q.z));
#pragma unroll
        for (int p = 0; p < 4; ++p) {
            __half2 m = __hfma2(exh, w0p[p], __hfma2(eyh, w1p[p], bcp[p]));
            __half2 t = pkmax2(__hadd2(bits2h2((&hq.x)[p]), m), zero2);
            float2 tf = __half22float2(t);
            acc[2 * p] += tf.x;
            acc[2 * p + 1] += tf.y;
        }
    }

    unsigned int o[4];
#pragma unroll
    for (int p = 0; p < 4; ++p) {
        float2 sf = __half22float2(bits2h2((&hs.x)[p]));
        o[p] = (unsigned int)f2bf(sf.x + acc[2 * p]) |
               ((unsigned int)f2bf(sf.y + acc[2 * p + 1]) << 16);
    }
    *(uint4*)&zbf[(size_t)n * HID + cg] = make_uint4(o[0], o[1], o[2], o[3]);
}

// ---------------- input GEMM (bf16 MFMA): hh = f16(x @ W_in + b_in) ----------------
__global__ __launch_bounds__(256) void ingemm_kernel(const float* __restrict__ A,
                                                     const unsigned short* __restrict__ Wt,
                                                     const float* __restrict__ bias,
                                                     unsigned short* __restrict__ outh) {
    constexpr int KD = IN_DIM;
    __shared__ unsigned short aS[64 * KD];
    __shared__ unsigned short wS[128 * KD];
    int tid = threadIdx.x;
    int row0 = blockIdx.x * 64;

#pragma unroll
    for (int it = 0; it < (64 * KD) / (256 * 4); ++it) {
        int idx = it * 1024 + tid * 4;
        int r = idx / KD, k = idx % KD;
        int grow = row0 + r;
        float4 v = (grow < N_NODES) ? *(const float4*)&A[(size_t)grow * KD + k]
                                    : make_float4(0.f, 0.f, 0.f, 0.f);
        unsigned int d0 = (unsigned int)f2bf(v.x) | ((unsigned int)f2bf(v.y) << 16);
        unsigned int d1 = (unsigned int)f2bf(v.z) | ((unsigned int)f2bf(v.w) << 16);
        unsigned int byte = (unsigned int)(idx * 2) ^ (unsigned int)((r & 7) << 4);
        *(uint2*)((char*)aS + byte) = make_uint2(d0, d1);
    }
#pragma unroll
    for (int it = 0; it < (128 * KD) / (256 * 8); ++it) {
        int idx = it * 2048 + tid * 8;
        int c = idx / KD;
        uint4 v = *(const uint4*)&Wt[idx];
        unsigned int byte = (unsigned int)(idx * 2) ^ (unsigned int)((c & 7) << 4);
        *(uint4*)((char*)wS + byte) = v;
    }
    __syncthreads();

    int w = tid >> 6, l = tid & 63;
    int wr = w >> 1, wc = w & 1, lr = l & 15, kq = (l >> 4) * 8;
    f32x4 acc[2][4];
#pragma unroll
    for (int r = 0; r < 2; ++r)
#pragma unroll
        for (int t = 0; t < 4; ++t) acc[r][t] = (f32x4){0.f, 0.f, 0.f, 0.f};

#pragma unroll
    for (int sstep = 0; sstep < KD / 32; ++sstep) {
        int k0 = sstep * 32 + kq;
        int ar0 = 32 * wr + lr, ar1 = ar0 + 16;
        short8 af0 = *(short8*)((char*)aS + ((unsigned int)((ar0 * KD + k0) * 2) ^
                                            (unsigned int)((ar0 & 7) << 4)));
        short8 af1 = *(short8*)((char*)aS + ((unsigned int)((ar1 * KD + k0) * 2) ^
                                            (unsigned int)((ar1 & 7) << 4)));
#pragma unroll
        for (int t = 0; t < 4; ++t) {
            int col = 64 * wc + 16 * t + lr;
            short8 bf = *(short8*)((char*)wS + ((unsigned int)((col * KD + k0) * 2) ^
                                               (unsigned int)((col & 7) << 4)));
            acc[0][t] = __builtin_amdgcn_mfma_f32_16x16x32_bf16(af0, bf, acc[0][t], 0, 0, 0);
            acc[1][t] = __builtin_amdgcn_mfma_f32_16x16x32_bf16(af1, bf, acc[1][t], 0, 0, 0);
        }
    }
#pragma unroll
    for (int r = 0; r < 2; ++r) {
        int rbase = row0 + 32 * wr + 16 * r + (l >> 4) * 4;
#pragma unroll
        for (int t = 0; t < 4; ++t) {
            int col = 64 * wc + 16 * t + lr;
            float b = bias[col];
#pragma unroll
            for (int q = 0; q < 4; ++q) {
                int grow = rbase + q;
                if (grow < N_NODES) outh[(size_t)grow * HID + col] = f2h_bits(acc[r][t][q] + b);
            }
        }
    }
}

// ---------------- fused conv MLP: z2 = relu(z@W1+b1)@W2+b2, + BN stats ----------------
// 128x128 tile, 512 threads = 8 waves (2x4). y lives in LDS (reuses z tile).
// BN stats shuffle-reduced across the 4 same-column lanes before LDS atomics.
__global__ __launch_bounds__(512) void conv_kernel(const unsigned short* __restrict__ zbf,
                                                   const unsigned short* __restrict__ Wt1,
                                                   const float* __restrict__ b1,
                                                   const unsigned short* __restrict__ Wt2,
                                                   const float* __restrict__ b2,
                                                   unsigned short* __restrict__ z2bf,
                                                   float* __restrict__ S1,
                                                   float* __restrict__ S2,
                                                   float* __restrict__ zinit, int zinit_n) {
    constexpr int KD = HID;
    __shared__ unsigned short aS[128 * KD];   // z tile, then y tile (32 KB)
    __shared__ unsigned short wS[128 * KD];   // W1, then W2 (32 KB)
    __shared__ float sh1[HID], sh2[HID];
    int tid = threadIdx.x;
    if (zinit && blockIdx.x == 0)
        for (int i = tid; i < zinit_n; i += 512) zinit[i] = 0.f;
    if (tid < HID) { sh1[tid] = 0.f; sh2[tid] = 0.f; }

    int row0 = blockIdx.x * 128;

#pragma unroll
    for (int it = 0; it < 4; ++it) {          // 128*128/(512*8)
        int idx = it * 4096 + tid * 8;
        int r = idx >> 7;
        int grow = row0 + r;
        uint4 v = (grow < N_NODES) ? *(const uint4*)&zbf[(size_t)grow * HID + (idx & 127)]
                                   : make_uint4(0u, 0u, 0u, 0u);
        unsigned int byte = (unsigned int)(idx * 2) ^ (unsigned int)((r & 7) << 4);
        *(uint4*)((char*)aS + byte) = v;
    }
#pragma unroll
    for (int it = 0; it < 4; ++it) {
        int idx = it * 4096 + tid * 8;
        int c = idx >> 7;
        uint4 v = *(const uint4*)&Wt1[idx];
        unsigned int byte = (unsigned int)(idx * 2) ^ (unsigned int)((c & 7) << 4);
        *(uint4*)((char*)wS + byte) = v;
    }
    __syncthreads();

    int w = tid >> 6, l = tid & 63;
    int wr = w >> 2, wc = w & 3;       // 2x4 wave grid: 64 rows x 32 cols per wave
    int lr = l & 15, kq = (l >> 4) * 8;

    f32x4 acc[4][2];
#pragma unroll
    for (int rt = 0; rt < 4; ++rt)
#pragma unroll
        for (int ct = 0; ct < 2; ++ct) acc[rt][ct] = (f32x4){0.f, 0.f, 0.f, 0.f};

#pragma unroll
    for (int sstep = 0; sstep < 4; ++sstep) {
        int k0 = sstep * 32 + kq;
        short8 af[4];
#pragma unroll
        for (int rt = 0; rt < 4; ++rt) {
            int ar = 64 * wr + 16 * rt + lr;
            af[rt] = *(short8*)((char*)aS + ((unsigned int)((ar * KD + k0) * 2) ^
                                            (unsigned int)((ar & 7) << 4)));
        }
#pragma unroll
        for (int ct = 0; ct < 2; ++ct) {
            int col = 32 * wc + 16 * ct + lr;
            short8 bf = *(short8*)((char*)wS + ((unsigned int)((col * KD + k0) * 2) ^
                                               (unsigned int)((col & 7) << 4)));
#pragma unroll
            for (int rt = 0; rt < 4; ++rt)
                acc[rt][ct] = __builtin_amdgcn_mfma_f32_16x16x32_bf16(af[rt], bf, acc[rt][ct], 0, 0, 0);
        }
    }
    __syncthreads();   // everyone done reading aS (z) and wS (W1)

    // y = relu(acc + b1) -> aS (bf16, swizzled); stage W2 -> wS
#pragma unroll
    for (int rt = 0; rt < 4; ++rt) {
        int lrow0 = 64 * wr + 16 * rt + (l >> 4) * 4;
#pragma unroll
        for (int ct = 0; ct < 2; ++ct) {
            int col = 32 * wc + 16 * ct + lr;
            float b = b1[col];
#pragma unroll
            for (int q = 0; q < 4; ++q) {
                int lrow = lrow0 + q;
                float v = fmaxf(acc[rt][ct][q] + b, 0.f);
                unsigned int byte = (unsigned int)((lrow * KD + col) * 2) ^
                                    (unsigned int)((lrow & 7) << 4);
                *(unsigned short*)((char*)aS + byte) = f2bf(v);
            }
        }
    }
#pragma unroll
    for (int it = 0; it < 4; ++it) {
        int idx = it * 4096 + tid * 8;
        int c = idx >> 7;
        uint4 v = *(const uint4*)&Wt2[idx];
        unsigned int byte = (unsigned int)(idx * 2) ^ (unsigned int)((c & 7) << 4);
        *(uint4*)((char*)wS + byte) = v;
    }
    __syncthreads();

    f32x4 acc2[4][2];
#pragma unroll
    for (int rt = 0; rt < 4; ++rt)
#pragma unroll
        for (int ct = 0; ct < 2; ++ct) acc2[rt][ct] = (f32x4){0.f, 0.f, 0.f, 0.f};

#pragma unroll
    for (int sstep = 0; sstep < 4; ++sstep) {
        int k0 = sstep * 32 + kq;
        short8 af[4];
#pragma unroll
        for (int rt = 0; rt < 4; ++rt) {
            int ar = 64 * wr + 16 * rt + lr;
            af[rt] = *(short8*)((char*)aS + ((unsigned int)((ar * KD + k0) * 2) ^
                                            (unsigned int)((ar & 7) << 4)));
        }
#pragma unroll
        for (int ct = 0; ct < 2; ++ct) {
            int col = 32 * wc + 16 * ct + lr;
            short8 bf = *(short8*)((char*)wS + ((unsigned int)((col * KD + k0) * 2) ^
                                               (unsigned int)((col & 7) << 4)));
#pragma unroll
            for (int rt = 0; rt < 4; ++rt)
                acc2[rt][ct] = __builtin_amdgcn_mfma_f32_16x16x32_bf16(af[rt], bf, acc2[rt][ct], 0, 0, 0);
        }
    }

    // epilogue: z2 = acc2 + b2 -> z2bf (bf16) + BN stats (register acc + shuffle reduce)
    float s1v[2] = {0.f, 0.f}, s2v[2] = {0.f, 0.f};
#pragma unroll
    for (int rt = 0; rt < 4; ++rt) {
        int rbase = row0 + 64 * wr + 16 * rt + (l >> 4) * 4;
#pragma unroll
        for (int ct = 0; ct < 2; ++ct) {
            int col = 32 * wc + 16 * ct + lr;
            float b = b2[col];
#pragma unroll
            for (int q = 0; q < 4; ++q) {
                int grow = rbase + q;
                if (grow < N_NODES) {
                    float v = acc2[rt][ct][q] + b;
                    z2bf[(size_t)grow * HID + col] = f2bf(v);
                    s1v[ct] += v;
                    s2v[ct] += v * v;
                }
            }
        }
    }
#pragma unroll
    for (int ct = 0; ct < 2; ++ct) {
        float a = s1v[ct], bsum2 = s2v[ct];
        a += __shfl_xor(a, 16); a += __shfl_xor(a, 32);
        bsum2 += __shfl_xor(bsum2, 16); bsum2 += __shfl_xor(bsum2, 32);
        if ((l >> 4) == 0) {
            int col = 32 * wc + 16 * ct + lr;
            atomicAdd(&sh1[col], a);
            atomicAdd(&sh2[col], bsum2);
        }
    }
    __syncthreads();
    if (tid < HID) {
        atomicAdd(&S1[tid], sh1[tid]);
        atomicAdd(&S2[tid], sh2[tid]);
    }
}

// ---------------- BN apply + relu -> hh (f16) + segment-sum into vn_up/pool ----------------
__global__ __launch_bounds__(256) void bn_kernel(const unsigned short* __restrict__ z2bf,
                                                 const float* __restrict__ S1,
                                                 const float* __restrict__ S2,
                                                 const float* __restrict__ gma,
                                                 const float* __restrict__ bta,
                                                 const int* __restrict__ batch,
                                                 unsigned short* __restrict__ hh,
                                                 float* __restrict__ up) {
    int tid = threadIdx.x;
    int cg = (tid & 31) * 4;
    int n0 = (blockIdx.x * 8 + (tid >> 5)) * 16;
    const float inv = 1.f / (float)N_NODES;
    float4 s1 = *(const float4*)&S1[cg];
    float4 s2 = *(const float4*)&S2[cg];
    float4 g4 = *(const float4*)&gma[cg];
    float4 b4 = *(const float4*)&bta[cg];
    float mux = s1.x * inv, muy = s1.y * inv, muz = s1.z * inv, muw = s1.w * inv;
    float gmx = g4.x * rsqrtf(s2.x * inv - mux * mux + BN_EPS);
    float gmy = g4.y * rsqrtf(s2.y * inv - muy * muy + BN_EPS);
    float gmz = g4.z * rsqrtf(s2.z * inv - muz * muz + BN_EPS);
    float gmw = g4.w * rsqrtf(s2.w * inv - muw * muw + BN_EPS);

    float4 acc = make_float4(0.f, 0.f, 0.f, 0.f);
    int gcur = -1;
    for (int i = 0; i < 16; ++i) {
        int n = n0 + i;
        if (n >= N_NODES) break;
        uint2 zv = *(const uint2*)&z2bf[(size_t)n * HID + cg];
        float4 hn;
        hn.x = fmaxf(fmaf(bflo(zv.x) - mux, gmx, b4.x), 0.f);
        hn.y = fmaxf(fmaf(bfhi(zv.x) - muy, gmy, b4.y), 0.f);
        hn.z = fmaxf(fmaf(bflo(zv.y) - muz, gmz, b4.z), 0.f);
        hn.w = fmaxf(fmaf(bfhi(zv.y) - muw, gmw, b4.w), 0.f);
        uint2 pk;
        pk.x = h2bits(__floats2half2_rn(hn.x, hn.y));
        pk.y = h2bits(__floats2half2_rn(hn.z, hn.w));
        *(uint2*)&hh[(size_t)n * HID + cg] = pk;
        int gb = batch[n];
        if (gb != gcur) {
            if (gcur >= 0) {
                atomicAdd(&up[gcur * HID + cg + 0], acc.x);
                atomicAdd(&up[gcur * HID + cg + 1], acc.y);
                atomicAdd(&up[gcur * HID + cg + 2], acc.z);
                atomicAdd(&up[gcur * HID + cg + 3], acc.w);
            }
            acc = make_float4(0.f, 0.f, 0.f, 0.f);
            gcur = gb;
        }
        acc.x += hn.x; acc.y += hn.y; acc.z += hn.z; acc.w += hn.w;
    }
    if (gcur >= 0) {
        atomicAdd(&up[gcur * HID + cg + 0], acc.x);
        atomicAdd(&up[gcur * HID + cg + 1], acc.y);
        atomicAdd(&up[gcur * HID + cg + 2], acc.z);
        atomicAdd(&up[gcur * HID + cg + 3], acc.w);
    }
}

// ---------------- virtual-node MLP: vn += relu(up@W1+b1)@W2+b2; also f16 copy ----------------
__global__ __launch_bounds__(128) void vnmlp_kernel(const float* __restrict__ up,
                                                    const float* __restrict__ W1,
                                                    const float* __restrict__ b1,
                                                    const float* __restrict__ W2,
                                                    const float* __restrict__ b2,
                                                    float* __restrict__ vn,
                                                    unsigned short* __restrict__ vnh) {
    __shared__ float t[HID];
    int g = blockIdx.x, c = threadIdx.x;
    float s = b1[c];
#pragma unroll 8
    for (int k = 0; k < HID; ++k) s = fmaf(up[g * HID + k], W1[k * HID + c], s);
    t[c] = fmaxf(s, 0.f);
    __syncthreads();
    float s2 = b2[c];
#pragma unroll 8
    for (int k = 0; k < HID; ++k) s2 = fmaf(t[k], W2[k * HID + c], s2);
    float nv = vn[g * HID + c] + s2;
    vn[g * HID + c] = nv;
    vnh[g * HID + c] = f2h_bits(nv);
}

// ---------------- classifier: logits[g] ----------------
__global__ __launch_bounds__(128) void cls_kernel(const float* __restrict__ pool,
                                                  const int* __restrict__ endpos,
                                                  const float* __restrict__ W1,
                                                  const float* __restrict__ b1,
                                                  const float* __restrict__ W2,
                                                  const float* __restrict__ b2,
                                                  float* __restrict__ out) {
    __shared__ float t[HID];
    __shared__ float red[HID];
    int g = blockIdx.x, c = threadIdx.x;
    int cnt = endpos[g] - (g > 0 ? endpos[g - 1] : 0);
    float cntf = fmaxf((float)cnt, 1.f);
    t[c] = pool[g * HID + c] / cntf;
    __syncthreads();
    float s = b1[c];
#pragma unroll 8
    for (int k = 0; k < HID; ++k) s = fmaf(t[k], W1[k * HID + c], s);
    float y = fmaxf(s, 0.f);
    red[c] = y * W2[c];
    __syncthreads();
    for (int off = 64; off > 0; off >>= 1) {
        if (c < off) red[c] += red[c + off];
        __syncthreads();
    }
    if (c == 0) out[g] = red[0] + b2[0];
}

// ---------------- host-side orchestration ----------------
extern "C" void kernel_launch(void* const* d_in, const int* in_sizes, int n_in,
                              void* d_out, int out_size, void* d_ws, size_t ws_size,
                              hipStream_t stream) {
    const float* x        = (const float*)d_in[0];
    const float* edge_attr= (const float*)d_in[1];
    const int*   edge_idx = (const int*)d_in[2];
    const int*   batch    = (const int*)d_in[3];
    const float* W_in     = (const float*)d_in[4];
    const float* b_in     = (const float*)d_in[5];
    const float* W_e      = (const float*)d_in[6];
    const float* b_e      = (const float*)d_in[7];
    const float* conv_W1  = (const float*)d_in[8];
    const float* conv_b1  = (const float*)d_in[9];
    const float* conv_W2  = (const float*)d_in[10];
    const float* conv_b2  = (const float*)d_in[11];
    const float* bn_g     = (const float*)d_in[12];
    const float* bn_b     = (const float*)d_in[13];
    const float* vn_W1    = (const float*)d_in[14];
    const float* vn_b1    = (const float*)d_in[15];
    const float* vn_W2    = (const float*)d_in[16];
    const float* vn_b2    = (const float*)d_in[17];
    const float* cls_W1   = (const float*)d_in[18];
    const float* cls_b1   = (const float*)d_in[19];
    const float* cls_W2   = (const float*)d_in[20];
    const float* cls_b2   = (const float*)d_in[21];

    char* ws = (char*)d_ws;
    size_t off = 0;
    auto alloc = [&](size_t bytes) -> void* {
        void* p = ws + off;
        off = (off + bytes + 255) & ~(size_t)255;
        return p;
    };
    unsigned short* z2bf = (unsigned short*)alloc((size_t)N_NODES * HID * 2);
    unsigned short* hh  = (unsigned short*)alloc((size_t)N_NODES * HID * 2);   // f16
    unsigned short* gh  = (unsigned short*)alloc((size_t)N_NODES * HID * 2);   // f16
    unsigned short* zbf = (unsigned short*)alloc((size_t)N_NODES * HID * 2);   // bf16
    size_t zero_begin = off;
    int*   cnt    = (int*)alloc((size_t)N_NODES * 4);
    float* vn     = (float*)alloc((size_t)NUM_GRAPHS * HID * 4);
    unsigned short* vnh = (unsigned short*)alloc((size_t)NUM_GRAPHS * HID * 2);  // f16
    float* pool   = (float*)alloc((size_t)NUM_GRAPHS * HID * 4);
    size_t zero_end = off;
    int*    endpos    = (int*)alloc((size_t)NUM_GRAPHS * 4);
    int*    row_start = (int*)alloc((size_t)(N_NODES + 1) * 4);
    int*    rank      = (int*)alloc((size_t)N_EDGES * 4);
    int4*   edges     = (int4*)alloc((size_t)N_EDGES * 16);
    float*  vn_up     = (float*)alloc((size_t)NUM_GRAPHS * HID * 4);
    float*  S1        = (float*)alloc((size_t)HID * 4);
    float*  S2        = (float*)alloc((size_t)HID * 4);
    int*    bsum      = (int*)alloc((size_t)SCAN_BLOCKS * 4);
    unsigned short* wt_in = (unsigned short*)alloc((size_t)HID * IN_DIM * 2);
    unsigned short* wt1   = (unsigned short*)alloc((size_t)NUM_LAYERS * HID * HID * 2);
    unsigned short* wt2   = (unsigned short*)alloc((size_t)NUM_LAYERS * HID * HID * 2);
    (void)ws_size; (void)in_sizes; (void)n_in; (void)out_size;

    const int* srcp = edge_idx;
    const int* dstp = edge_idx + N_EDGES;

    (void)hipMemsetAsync(ws + zero_begin, 0, zero_end - zero_begin, stream);
    prep_kernel<<<(N_EDGES + 1023) / 1024, 256, 0, stream>>>(dstp, cnt, rank, batch, endpos,
                                                             W_in, conv_W1, conv_W2,
                                                             wt_in, wt1, wt2);
    scan1_kernel<<<SCAN_BLOCKS, 1024, 0, stream>>>(cnt, bsum);
    scan3_kernel<<<SCAN_BLOCKS, 1024, 0, stream>>>(cnt, bsum, row_start);
    fill_kernel<<<(N_EDGES + 255) / 256, 256, 0, stream>>>(srcp, dstp, edge_attr, rank,
                                                           row_start, edges);

    ingemm_kernel<<<(N_NODES + 63) / 64, 256, 0, stream>>>(x, wt_in, b_in, hh);

    const int conv_grid = (N_NODES + 127) / 128;   // 391
    for (int i = 0; i < NUM_LAYERS; ++i) {
        const unsigned short* src_tab = hh;
        if (i > 0) {
            hvadd_kernel<<<(N_NODES * 16 + 255) / 256, 256, 0, stream>>>(hh, vnh, batch, gh);
            src_tab = gh;
        }
        aggr_kernel<<<N_NODES / 16, 256, 0, stream>>>(src_tab, edges, row_start,
                                                      W_e, b_e, zbf, S1, S2);
        conv_kernel<<<conv_grid, 512, 0, stream>>>(
            zbf, wt1 + (size_t)i * HID * HID, conv_b1 + (size_t)i * HID,
            wt2 + (size_t)i * HID * HID, conv_b2 + (size_t)i * HID,
            z2bf, S1, S2, (i < NUM_LAYERS - 1) ? vn_up : nullptr, NUM_GRAPHS * HID);
        bn_kernel<<<(N_NODES + 127) / 128, 256, 0, stream>>>(z2bf, S1, S2, bn_g + (size_t)i * HID,
                                                             bn_b + (size_t)i * HID, batch, hh,
                                                             (i < NUM_LAYERS - 1) ? vn_up : pool);
        if (i < NUM_LAYERS - 1)
            vnmlp_kernel<<<NUM_GRAPHS, 128, 0, stream>>>(vn_up, vn_W1, vn_b1, vn_W2, vn_b2,
                                                         vn, vnh);
    }

    cls_kernel<<<NUM_GRAPHS, 128, 0, stream>>>(pool, endpos, cls_W1, cls_b1, cls_W2, cls_b2,
                                               (float*)d_out);
}